// Round 3
// baseline (1173.112 us; speedup 1.0000x reference)
//
#include <hip/hip_runtime.h>
#include <hip/hip_bf16.h>

typedef __bf16 bf16x8 __attribute__((ext_vector_type(8)));
typedef float f32x4 __attribute__((ext_vector_type(4)));

#define DEV __device__ __forceinline__

static constexpr int N_SENTC = 256, BB = 512, SS = 128, DD = 1024;
static constexpr int LL = 10331, LATENT = 101;

DEV unsigned short f2bf(float f) {
  unsigned u = __builtin_bit_cast(unsigned, f);
  unsigned lsb = (u >> 16) & 1u;
  u += 0x7fffu + lsb;
  return (unsigned short)(u >> 16);
}

// convert 8 contiguous f32 -> 8 bf16, store 16B to LDS
DEV void stage8(unsigned short* dst, const float* src) {
  float4 a = *(const float4*)src;
  float4 b = *(const float4*)(src + 4);
  unsigned short t[8];
  t[0] = f2bf(a.x); t[1] = f2bf(a.y); t[2] = f2bf(a.z); t[3] = f2bf(a.w);
  t[4] = f2bf(b.x); t[5] = f2bf(b.y); t[6] = f2bf(b.z); t[7] = f2bf(b.w);
  *(uint4*)dst = *(uint4*)t;
}

// ---------------------------------------------------------------------------
// men score GEMM: rows = 32768 sentence rows of X [32768,1024] (f32),
// cols e = 1024. score[row] += sum_e tanh(X.W^T) * w_o[e]
// grid = 512 rowTiles * 16 eTiles
// ---------------------------------------------------------------------------
__global__ __launch_bounds__(256) void k_men_gemm(
    const float* __restrict__ X, const float* __restrict__ Wm,
    const float* __restrict__ wo, float* __restrict__ score) {
  __shared__ __align__(16) unsigned short As[64 * 32];
  __shared__ __align__(16) unsigned short Bs[64 * 32];
  const int bid = blockIdx.x;
  const int rowBase = (bid >> 4) * 64, colBase = (bid & 15) * 64;
  const int tid = threadIdx.x, wave = tid >> 6, lane = tid & 63;
  const int lm = lane & 15, lq = lane >> 4;
  const int sr = tid >> 2, sc = (tid & 3) * 8;
  f32x4 acc[4] = {};
  for (int k0 = 0; k0 < 1024; k0 += 32) {
    __syncthreads();
    stage8(&As[sr * 32 + sc], &X[(size_t)(rowBase + sr) * 1024 + k0 + sc]);
    stage8(&Bs[sr * 32 + sc], &Wm[(size_t)(colBase + sr) * 1024 + k0 + sc]);
    __syncthreads();
    bf16x8 af = *(const bf16x8*)&As[(wave * 16 + lm) * 32 + lq * 8];
#pragma unroll
    for (int j = 0; j < 4; ++j) {
      bf16x8 bfr = *(const bf16x8*)&Bs[(j * 16 + lm) * 32 + lq * 8];
      acc[j] = __builtin_amdgcn_mfma_f32_16x16x32_bf16(af, bfr, acc[j], 0, 0, 0);
    }
  }
  float rsum[4] = {0.f, 0.f, 0.f, 0.f};
#pragma unroll
  for (int j = 0; j < 4; ++j) {
    float w = wo[colBase + j * 16 + lm];
#pragma unroll
    for (int r = 0; r < 4; ++r) rsum[r] += tanhf(acc[j][r]) * w;
  }
#pragma unroll
  for (int m = 1; m <= 8; m <<= 1)
#pragma unroll
    for (int r = 0; r < 4; ++r) rsum[r] += __shfl_xor(rsum[r], m, 64);
  if (lm == 0) {
    int row0 = rowBase + wave * 16 + lq * 4;
#pragma unroll
    for (int r = 0; r < 4; ++r) atomicAdd(&score[row0 + r], rsum[r]);
  }
}

// ---------------------------------------------------------------------------
// ctx score GEMM: rows = 65536 (b,s) rows (gathered), cols e = 1024.
// score[b,s] += sum_e tanh(X.Wc^T + cb[b,e] + dist[b,s]*wd[e]) * wo[e]
// grid = 1024 rowTiles * 16 eTiles
// ---------------------------------------------------------------------------
__global__ __launch_bounds__(256) void k_ctx_gemm(
    const float* __restrict__ X, const int* __restrict__ gathers,
    const float* __restrict__ Wc, const float* __restrict__ wd,
    const float* __restrict__ wo, const float* __restrict__ dist,
    const float* __restrict__ cb, float* __restrict__ score) {
  __shared__ __align__(16) unsigned short As[64 * 32];
  __shared__ __align__(16) unsigned short Bs[64 * 32];
  const int bid = blockIdx.x;
  const int rowBase = (bid >> 4) * 64, colBase = (bid & 15) * 64;
  const int tid = threadIdx.x, wave = tid >> 6, lane = tid & 63;
  const int lm = lane & 15, lq = lane >> 4;
  const int sr = tid >> 2, sc = (tid & 3) * 8;
  const int row_g = rowBase + sr;
  const int srcRow = (gathers[row_g >> 7] << 7) + (row_g & 127);
  f32x4 acc[4] = {};
  for (int k0 = 0; k0 < 1024; k0 += 32) {
    __syncthreads();
    stage8(&As[sr * 32 + sc], &X[(size_t)srcRow * 1024 + k0 + sc]);
    stage8(&Bs[sr * 32 + sc], &Wc[(size_t)(colBase + sr) * 1024 + k0 + sc]);
    __syncthreads();
    bf16x8 af = *(const bf16x8*)&As[(wave * 16 + lm) * 32 + lq * 8];
#pragma unroll
    for (int j = 0; j < 4; ++j) {
      bf16x8 bfr = *(const bf16x8*)&Bs[(j * 16 + lm) * 32 + lq * 8];
      acc[j] = __builtin_amdgcn_mfma_f32_16x16x32_bf16(af, bfr, acc[j], 0, 0, 0);
    }
  }
  float rsum[4] = {0.f, 0.f, 0.f, 0.f};
#pragma unroll
  for (int j = 0; j < 4; ++j) {
    int col = colBase + j * 16 + lm;
    float w = wo[col];
    float wdv = wd[col];
#pragma unroll
    for (int r = 0; r < 4; ++r) {
      int rg = rowBase + wave * 16 + lq * 4 + r;
      int b = rg >> 7, s = rg & 127;
      float v = acc[j][r] + cb[b * 1024 + col] + dist[b * 128 + s] * wdv;
      rsum[r] += tanhf(v) * w;
    }
  }
#pragma unroll
  for (int m = 1; m <= 8; m <<= 1)
#pragma unroll
    for (int r = 0; r < 4; ++r) rsum[r] += __shfl_xor(rsum[r], m, 64);
  if (lm == 0) {
    int row0 = rowBase + wave * 16 + lq * 4;
#pragma unroll
    for (int r = 0; r < 4; ++r) atomicAdd(&score[row0 + r], rsum[r]);
  }
}

// ---------------------------------------------------------------------------
// softmax over S=128 + weighted sum -> final_repr half. One block per b.
// ---------------------------------------------------------------------------
__global__ __launch_bounds__(256) void k_soft(
    const float* __restrict__ score_src, const float* __restrict__ mask,
    const float* __restrict__ X, const int* __restrict__ gathers,
    float* __restrict__ finalr, int isCtx) {
  const int b = blockIdx.x, tid = threadIdx.x;
  const int n = gathers[b];
  __shared__ float attn[128];
  __shared__ float smax, ssum;
  if (tid < 128) {
    int srow = isCtx ? b : n;
    float v = score_src[srow * 128 + tid] + (1.0f - mask[b * 128 + tid]) * (-10000.0f);
    attn[tid] = v;
  }
  __syncthreads();
  if (tid == 0) {
    float m = attn[0];
    for (int i = 1; i < 128; ++i) m = fmaxf(m, attn[i]);
    smax = m;
  }
  __syncthreads();
  if (tid < 128) attn[tid] = expf(attn[tid] - smax);
  __syncthreads();
  if (tid == 0) {
    float s = 0.f;
    for (int i = 0; i < 128; ++i) s += attn[i];
    ssum = 1.0f / s;
  }
  __syncthreads();
  if (tid < 128) attn[tid] *= ssum;
  __syncthreads();
  const float* xb = &X[(size_t)(n << 7) * 1024];
  const int off = isCtx ? 1024 : 0;
  for (int d = tid; d < 1024; d += 256) {
    float a = 0.f;
#pragma unroll 8
    for (int s = 0; s < 128; ++s) a += attn[s] * xb[s * 1024 + d];
    finalr[b * 2048 + off + d] = a;
  }
}

// ---------------------------------------------------------------------------
// cb GEMM: cb[b,e] = men_repr[b,:] . W_ctx_m[e,:]  (A = finalr f32 rows, stride 2048)
// grid = 8 rowTiles * 16 eTiles
// ---------------------------------------------------------------------------
__global__ __launch_bounds__(256) void k_cb_gemm(
    const float* __restrict__ finalr, const float* __restrict__ Wcm,
    float* __restrict__ cb) {
  __shared__ __align__(16) unsigned short As[64 * 32];
  __shared__ __align__(16) unsigned short Bs[64 * 32];
  const int bid = blockIdx.x;
  const int rowBase = (bid >> 4) * 64, colBase = (bid & 15) * 64;
  const int tid = threadIdx.x, wave = tid >> 6, lane = tid & 63;
  const int lm = lane & 15, lq = lane >> 4;
  const int sr = tid >> 2, sc = (tid & 3) * 8;
  f32x4 acc[4] = {};
  for (int k0 = 0; k0 < 1024; k0 += 32) {
    __syncthreads();
    stage8(&As[sr * 32 + sc], &finalr[(size_t)(rowBase + sr) * 2048 + k0 + sc]);
    stage8(&Bs[sr * 32 + sc], &Wcm[(size_t)(colBase + sr) * 1024 + k0 + sc]);
    __syncthreads();
    bf16x8 af = *(const bf16x8*)&As[(wave * 16 + lm) * 32 + lq * 8];
#pragma unroll
    for (int j = 0; j < 4; ++j) {
      bf16x8 bfr = *(const bf16x8*)&Bs[(j * 16 + lm) * 32 + lq * 8];
      acc[j] = __builtin_amdgcn_mfma_f32_16x16x32_bf16(af, bfr, acc[j], 0, 0, 0);
    }
  }
#pragma unroll
  for (int j = 0; j < 4; ++j) {
    int col = colBase + j * 16 + lm;
#pragma unroll
    for (int r = 0; r < 4; ++r) {
      int row = rowBase + wave * 16 + lq * 4 + r;
      cb[row * 1024 + col] = acc[j][r];
    }
  }
}

// ---------------------------------------------------------------------------
// latent GEMM: lat[b,l] = final[b,:2048] . W_f2l[l,:]; l < 101
// grid: dim3(2, 8) -> colTile, rowTile
// ---------------------------------------------------------------------------
__global__ __launch_bounds__(256) void k_lat_gemm(
    const float* __restrict__ finalr, const float* __restrict__ Wf2l,
    float* __restrict__ lat) {
  __shared__ __align__(16) unsigned short As[64 * 32];
  __shared__ __align__(16) unsigned short Bs[64 * 32];
  const int rowBase = blockIdx.y * 64, colBase = blockIdx.x * 64;
  const int tid = threadIdx.x, wave = tid >> 6, lane = tid & 63;
  const int lm = lane & 15, lq = lane >> 4;
  const int sr = tid >> 2, sc = (tid & 3) * 8;
  f32x4 acc[4] = {};
  for (int k0 = 0; k0 < 2048; k0 += 32) {
    __syncthreads();
    stage8(&As[sr * 32 + sc], &finalr[(size_t)(rowBase + sr) * 2048 + k0 + sc]);
    int l = colBase + sr;
    if (l < LATENT) {
      stage8(&Bs[sr * 32 + sc], &Wf2l[(size_t)l * 2048 + k0 + sc]);
    } else {
      uint4 z = {0, 0, 0, 0};
      *(uint4*)&Bs[sr * 32 + sc] = z;
    }
    __syncthreads();
    bf16x8 af = *(const bf16x8*)&As[(wave * 16 + lm) * 32 + lq * 8];
#pragma unroll
    for (int j = 0; j < 4; ++j) {
      bf16x8 bfr = *(const bf16x8*)&Bs[(j * 16 + lm) * 32 + lq * 8];
      acc[j] = __builtin_amdgcn_mfma_f32_16x16x32_bf16(af, bfr, acc[j], 0, 0, 0);
    }
  }
#pragma unroll
  for (int j = 0; j < 4; ++j) {
    int col = colBase + j * 16 + lm;
    if (col < LATENT) {
#pragma unroll
      for (int r = 0; r < 4; ++r) {
        int row = rowBase + wave * 16 + lq * 4 + r;
        lat[row * LATENT + col] = acc[j][r];
      }
    }
  }
}

// ---------------------------------------------------------------------------
// output GEMM:
//   outLat[b,l] = lat[b,:101] . W_l2l[l,:101]           (output 1, [512,10331])
//   out[b,l]    = final[b,:2048].W_out[l,:] + scal * outLat[b,l]  (output 0)
// latent term as 4 zero-padded K-steps into a separate accumulator.
// grid dim3(162, 8)
// ---------------------------------------------------------------------------
__global__ __launch_bounds__(256) void k_out_gemm(
    const float* __restrict__ finalr, const float* __restrict__ Wout,
    const float* __restrict__ lat, const float* __restrict__ Wl2l,
    const float* __restrict__ lscale, float* __restrict__ out,
    float* __restrict__ outLat) {
  __shared__ __align__(16) unsigned short As[64 * 32];
  __shared__ __align__(16) unsigned short Bs[64 * 32];
  const int rowBase = blockIdx.y * 64, colBase = blockIdx.x * 64;
  const int tid = threadIdx.x, wave = tid >> 6, lane = tid & 63;
  const int lm = lane & 15, lq = lane >> 4;
  const int sr = tid >> 2, sc = (tid & 3) * 8;
  const float scal = lscale[0];
  const int lrow = colBase + sr;
  const bool lvalid = (lrow < LL);
  f32x4 acc[4] = {};
  for (int k0 = 0; k0 < 2048; k0 += 32) {
    __syncthreads();
    stage8(&As[sr * 32 + sc], &finalr[(size_t)(rowBase + sr) * 2048 + k0 + sc]);
    if (lvalid) {
      stage8(&Bs[sr * 32 + sc], &Wout[(size_t)lrow * 2048 + k0 + sc]);
    } else {
      uint4 z = {0, 0, 0, 0};
      *(uint4*)&Bs[sr * 32 + sc] = z;
    }
    __syncthreads();
    bf16x8 af = *(const bf16x8*)&As[(wave * 16 + lm) * 32 + lq * 8];
#pragma unroll
    for (int j = 0; j < 4; ++j) {
      bf16x8 bfr = *(const bf16x8*)&Bs[(j * 16 + lm) * 32 + lq * 8];
      acc[j] = __builtin_amdgcn_mfma_f32_16x16x32_bf16(af, bfr, acc[j], 0, 0, 0);
    }
  }
  // latent @ W_l2l^T (unscaled), K padded 101 -> 128, separate accumulator
  f32x4 acc2[4] = {};
  for (int k2 = 0; k2 < 128; k2 += 32) {
    __syncthreads();
    const int brow = rowBase + sr;
#pragma unroll
    for (int jj = 0; jj < 8; ++jj) {
      int idx = k2 + sc + jj;
      As[sr * 32 + sc + jj] = (idx < LATENT) ? f2bf(lat[brow * LATENT + idx]) : (unsigned short)0;
      Bs[sr * 32 + sc + jj] = (lvalid && idx < LATENT) ? f2bf(Wl2l[lrow * LATENT + idx]) : (unsigned short)0;
    }
    __syncthreads();
    bf16x8 af = *(const bf16x8*)&As[(wave * 16 + lm) * 32 + lq * 8];
#pragma unroll
    for (int j = 0; j < 4; ++j) {
      bf16x8 bfr = *(const bf16x8*)&Bs[(j * 16 + lm) * 32 + lq * 8];
      acc2[j] = __builtin_amdgcn_mfma_f32_16x16x32_bf16(af, bfr, acc2[j], 0, 0, 0);
    }
  }
#pragma unroll
  for (int j = 0; j < 4; ++j) {
    int col = colBase + j * 16 + lm;
    if (col < LL) {
#pragma unroll
      for (int r = 0; r < 4; ++r) {
        int row = rowBase + wave * 16 + lq * 4 + r;
        float lv = acc2[j][r];
        out[(size_t)row * LL + col] = acc[j][r] + scal * lv;
        outLat[(size_t)row * LL + col] = lv;
      }
    }
  }
}

extern "C" void kernel_launch(void* const* d_in, const int* in_sizes, int n_in,
                              void* d_out, int out_size, void* d_ws, size_t ws_size,
                              hipStream_t stream) {
  const float* X = (const float*)d_in[0];
  const float* men_mask = (const float*)d_in[1];
  const float* ctx_mask = (const float*)d_in[2];
  const float* dist = (const float*)d_in[3];
  const int* gathers = (const int*)d_in[4];
  const float* W_men_m = (const float*)d_in[5];
  const float* W_men_o = (const float*)d_in[6];
  const float* W_ctx_c = (const float*)d_in[7];
  const float* W_ctx_m = (const float*)d_in[8];
  const float* w_ctx_d = (const float*)d_in[9];
  const float* W_ctx_o = (const float*)d_in[10];
  const float* W_out = (const float*)d_in[11];
  const float* W_f2l = (const float*)d_in[12];
  const float* W_l2l = (const float*)d_in[13];
  const float* lscale = (const float*)d_in[14];
  float* out = (float*)d_out;
  float* outLat = out + (size_t)BB * LL;  // output 1: [512, 10331]

  float* ws = (float*)d_ws;
  float* sent_score = ws;                      // 32768
  float* ctx_score = ws + 32768;               // 65536
  float* finalr = ws + 32768 + 65536;          // 512*2048
  float* cb = finalr + 512 * 2048;             // 512*1024
  float* lat = cb + 512 * 1024;                // 512*101

  hipMemsetAsync(d_ws, 0, (32768 + 65536) * sizeof(float), stream);
  k_men_gemm<<<8192, 256, 0, stream>>>(X, W_men_m, W_men_o, sent_score);
  k_soft<<<512, 256, 0, stream>>>(sent_score, men_mask, X, gathers, finalr, 0);
  k_cb_gemm<<<128, 256, 0, stream>>>(finalr, W_ctx_m, cb);
  k_ctx_gemm<<<16384, 256, 0, stream>>>(X, gathers, W_ctx_c, w_ctx_d, W_ctx_o, dist, cb, ctx_score);
  k_soft<<<512, 256, 0, stream>>>(ctx_score, ctx_mask, X, gathers, finalr, 1);
  k_lat_gemm<<<dim3(2, 8), 256, 0, stream>>>(finalr, W_f2l, lat);
  k_out_gemm<<<dim3(162, 8), 256, 0, stream>>>(finalr, W_out, lat, W_l2l, lscale, out, outLat);
}

// Round 4
// 932.728 us; speedup vs baseline: 1.2577x; 1.2577x over previous
//
#include <hip/hip_runtime.h>
#include <hip/hip_bf16.h>

typedef __bf16 bf16x8 __attribute__((ext_vector_type(8)));
typedef float f32x4 __attribute__((ext_vector_type(4)));

#define DEV __device__ __forceinline__

static constexpr int N_SENTC = 256, BB = 512, SS = 128, DD = 1024;
static constexpr int LL = 10331, LATENT = 101;

DEV float bf2f(unsigned short u) {
  unsigned v = (unsigned)u << 16;
  return __builtin_bit_cast(float, v);
}
DEV unsigned short f2bf(float f) {
  unsigned u = __builtin_bit_cast(unsigned, f);
  unsigned lsb = (u >> 16) & 1u;
  u += 0x7fffu + lsb;
  return (unsigned short)(u >> 16);
}

// convert 8 contiguous f32 -> 8 bf16, store 16B to LDS
DEV void stage8(unsigned short* dst, const float* src) {
  float4 a = *(const float4*)src;
  float4 b = *(const float4*)(src + 4);
  unsigned short t[8];
  t[0] = f2bf(a.x); t[1] = f2bf(a.y); t[2] = f2bf(a.z); t[3] = f2bf(a.w);
  t[4] = f2bf(b.x); t[5] = f2bf(b.y); t[6] = f2bf(b.z); t[7] = f2bf(b.w);
  *(uint4*)dst = *(uint4*)t;
}

// ---------------------------------------------------------------------------
// f32 -> bf16 bulk convert (n4 = n/4 float4 groups)
// ---------------------------------------------------------------------------
__global__ __launch_bounds__(256) void k_cvt(
    const float* __restrict__ src, unsigned short* __restrict__ dst, int n4) {
  for (int i = blockIdx.x * 256 + threadIdx.x; i < n4; i += gridDim.x * 256) {
    float4 v = ((const float4*)src)[i];
    unsigned short t[4] = {f2bf(v.x), f2bf(v.y), f2bf(v.z), f2bf(v.w)};
    ((uint2*)dst)[i] = *(const uint2*)t;
  }
}

// ---------------------------------------------------------------------------
// Fused men-score + ctx-hidden GEMM over the 32768 unique sentence rows.
// A = Xb [32768,1024] bf16. colTile<8: B=Wmb, epilogue tanh*wo -> atomic men
// score. colTile>=8: B=Wcb, epilogue stores Hc bf16 [32768,1024].
// 128x128 block tile, 4 waves, each wave 64x64 (4x4 16x16x32 frags).
// LDS row stride 40 bf16 (80B) to spread ds_read_b128 bank phases.
// grid = dim3(16, 256)
// ---------------------------------------------------------------------------
__global__ __launch_bounds__(256) void k_mc_gemm(
    const unsigned short* __restrict__ Xb, const unsigned short* __restrict__ Wmb,
    const unsigned short* __restrict__ Wcb, const float* __restrict__ wo,
    float* __restrict__ score, unsigned short* __restrict__ Hc) {
  constexpr int LS = 40;  // LDS row stride in bf16
  __shared__ __align__(16) unsigned short As[128 * LS];
  __shared__ __align__(16) unsigned short Bs[128 * LS];
  const int colTile = blockIdx.x;
  const int rowBase = blockIdx.y * 128;
  const bool isMen = colTile < 8;
  const unsigned short* __restrict__ Bsrc = isMen ? Wmb : Wcb;
  const int bcolBase = (isMen ? colTile : colTile - 8) * 128;
  const int tid = threadIdx.x, wave = tid >> 6, lane = tid & 63;
  const int lm = lane & 15, lq = lane >> 4;
  const int wr = (wave & 1) * 64, wc = (wave >> 1) * 64;
  const int sr = tid >> 1, sc = (tid & 1) * 16;
  const unsigned short* aRow = &Xb[(size_t)(rowBase + sr) * 1024 + sc];
  const unsigned short* bRow = &Bsrc[(size_t)(bcolBase + sr) * 1024 + sc];
  f32x4 acc[4][4] = {};
  for (int k0 = 0; k0 < 1024; k0 += 32) {
    uint4 a0 = *(const uint4*)(aRow + k0);
    uint4 a1 = *(const uint4*)(aRow + k0 + 8);
    uint4 b0 = *(const uint4*)(bRow + k0);
    uint4 b1 = *(const uint4*)(bRow + k0 + 8);
    __syncthreads();
    *(uint4*)&As[sr * LS + sc] = a0;
    *(uint4*)&As[sr * LS + sc + 8] = a1;
    *(uint4*)&Bs[sr * LS + sc] = b0;
    *(uint4*)&Bs[sr * LS + sc + 8] = b1;
    __syncthreads();
    bf16x8 af[4], bfr[4];
#pragma unroll
    for (int m = 0; m < 4; ++m)
      af[m] = *(const bf16x8*)&As[(wr + m * 16 + lm) * LS + lq * 8];
#pragma unroll
    for (int n = 0; n < 4; ++n)
      bfr[n] = *(const bf16x8*)&Bs[(wc + n * 16 + lm) * LS + lq * 8];
#pragma unroll
    for (int m = 0; m < 4; ++m)
#pragma unroll
      for (int n = 0; n < 4; ++n)
        acc[m][n] = __builtin_amdgcn_mfma_f32_16x16x32_bf16(af[m], bfr[n], acc[m][n], 0, 0, 0);
  }
  if (isMen) {
    float wov[4];
#pragma unroll
    for (int n = 0; n < 4; ++n) wov[n] = wo[bcolBase + wc + n * 16 + lm];
    float rsum[4][4];
#pragma unroll
    for (int m = 0; m < 4; ++m)
#pragma unroll
      for (int r = 0; r < 4; ++r) {
        float s = 0.f;
#pragma unroll
        for (int n = 0; n < 4; ++n) s += tanhf(acc[m][n][r]) * wov[n];
        rsum[m][r] = s;
      }
#pragma unroll
    for (int msk = 1; msk <= 8; msk <<= 1)
#pragma unroll
      for (int m = 0; m < 4; ++m)
#pragma unroll
        for (int r = 0; r < 4; ++r) rsum[m][r] += __shfl_xor(rsum[m][r], msk, 64);
    if (lm == 0) {
#pragma unroll
      for (int m = 0; m < 4; ++m)
#pragma unroll
        for (int r = 0; r < 4; ++r)
          atomicAdd(&score[rowBase + wr + m * 16 + lq * 4 + r], rsum[m][r]);
    }
  } else {
#pragma unroll
    for (int m = 0; m < 4; ++m)
#pragma unroll
      for (int n = 0; n < 4; ++n) {
        int col = bcolBase + wc + n * 16 + lm;
#pragma unroll
        for (int r = 0; r < 4; ++r) {
          int row = rowBase + wr + m * 16 + lq * 4 + r;
          Hc[(size_t)row * 1024 + col] = f2bf(acc[m][n][r]);
        }
      }
  }
}

// ---------------------------------------------------------------------------
// ctx score from deduped hidden: score[b,s] =
//   sum_e tanh(Hc[n(b)*128+s, e] + cb[b,e] + dist[b,s]*wd[e]) * wo[e]
// one block per b; one wave per s (4 s at a time).
// ---------------------------------------------------------------------------
__global__ __launch_bounds__(256) void k_ctx_score(
    const unsigned short* __restrict__ Hc, const int* __restrict__ gathers,
    const float* __restrict__ cb, const float* __restrict__ wd,
    const float* __restrict__ wo, const float* __restrict__ dist,
    float* __restrict__ score) {
  const int b = blockIdx.x, tid = threadIdx.x, wave = tid >> 6, lane = tid & 63;
  const int n = gathers[b];
  __shared__ float cbl[1024], wdl[1024], wol[1024];
  for (int i = tid; i < 1024; i += 256) {
    cbl[i] = cb[b * 1024 + i];
    wdl[i] = wd[i];
    wol[i] = wo[i];
  }
  __syncthreads();
  for (int s = wave; s < 128; s += 4) {
    float d = dist[b * 128 + s];
    const unsigned short* hrow = &Hc[(size_t)(n * 128 + s) * 1024 + lane * 16];
    unsigned short hs[16];
    *(uint4*)hs = *(const uint4*)hrow;
    *(uint4*)(hs + 8) = *(const uint4*)(hrow + 8);
    float p = 0.f;
#pragma unroll
    for (int j = 0; j < 16; ++j) {
      int e = lane * 16 + j;
      p += tanhf(bf2f(hs[j]) + cbl[e] + d * wdl[e]) * wol[e];
    }
#pragma unroll
    for (int msk = 1; msk <= 32; msk <<= 1) p += __shfl_xor(p, msk, 64);
    if (lane == 0) score[b * 128 + s] = p;
  }
}

// ---------------------------------------------------------------------------
// softmax over S=128 + weighted sum -> final_repr half. One block per b.
// ---------------------------------------------------------------------------
__global__ __launch_bounds__(256) void k_soft(
    const float* __restrict__ score_src, const float* __restrict__ mask,
    const float* __restrict__ X, const int* __restrict__ gathers,
    float* __restrict__ finalr, int isCtx) {
  const int b = blockIdx.x, tid = threadIdx.x;
  const int n = gathers[b];
  __shared__ float attn[128];
  __shared__ float smax, ssum;
  if (tid < 128) {
    int srow = isCtx ? b : n;
    float v = score_src[srow * 128 + tid] + (1.0f - mask[b * 128 + tid]) * (-10000.0f);
    attn[tid] = v;
  }
  __syncthreads();
  if (tid == 0) {
    float m = attn[0];
    for (int i = 1; i < 128; ++i) m = fmaxf(m, attn[i]);
    smax = m;
  }
  __syncthreads();
  if (tid < 128) attn[tid] = expf(attn[tid] - smax);
  __syncthreads();
  if (tid == 0) {
    float s = 0.f;
    for (int i = 0; i < 128; ++i) s += attn[i];
    ssum = 1.0f / s;
  }
  __syncthreads();
  if (tid < 128) attn[tid] *= ssum;
  __syncthreads();
  const float* xb = &X[(size_t)(n << 7) * 1024];
  const int off = isCtx ? 1024 : 0;
  for (int d = tid; d < 1024; d += 256) {
    float a = 0.f;
#pragma unroll 8
    for (int s = 0; s < 128; ++s) a += attn[s] * xb[s * 1024 + d];
    finalr[b * 2048 + off + d] = a;
  }
}

// ---------------------------------------------------------------------------
// cb GEMM: cb[b,e] = men_repr[b,:] . W_ctx_m[e,:]  (A = finalr f32, stride 2048)
// grid = 8 rowTiles * 16 eTiles
// ---------------------------------------------------------------------------
__global__ __launch_bounds__(256) void k_cb_gemm(
    const float* __restrict__ finalr, const float* __restrict__ Wcm,
    float* __restrict__ cb) {
  __shared__ __align__(16) unsigned short As[64 * 32];
  __shared__ __align__(16) unsigned short Bs[64 * 32];
  const int bid = blockIdx.x;
  const int rowBase = (bid >> 4) * 64, colBase = (bid & 15) * 64;
  const int tid = threadIdx.x, wave = tid >> 6, lane = tid & 63;
  const int lm = lane & 15, lq = lane >> 4;
  const int sr = tid >> 2, sc = (tid & 3) * 8;
  f32x4 acc[4] = {};
  for (int k0 = 0; k0 < 1024; k0 += 32) {
    __syncthreads();
    stage8(&As[sr * 32 + sc], &finalr[(size_t)(rowBase + sr) * 2048 + k0 + sc]);
    stage8(&Bs[sr * 32 + sc], &Wcm[(size_t)(colBase + sr) * 1024 + k0 + sc]);
    __syncthreads();
    bf16x8 af = *(const bf16x8*)&As[(wave * 16 + lm) * 32 + lq * 8];
#pragma unroll
    for (int j = 0; j < 4; ++j) {
      bf16x8 bfr = *(const bf16x8*)&Bs[(j * 16 + lm) * 32 + lq * 8];
      acc[j] = __builtin_amdgcn_mfma_f32_16x16x32_bf16(af, bfr, acc[j], 0, 0, 0);
    }
  }
#pragma unroll
  for (int j = 0; j < 4; ++j) {
    int col = colBase + j * 16 + lm;
#pragma unroll
    for (int r = 0; r < 4; ++r) {
      int row = rowBase + wave * 16 + lq * 4 + r;
      cb[row * 1024 + col] = acc[j][r];
    }
  }
}

// ---------------------------------------------------------------------------
// latent GEMM: lat[b,l] = final[b,:2048] . W_f2l[l,:]; l < 101
// grid: dim3(2, 8)
// ---------------------------------------------------------------------------
__global__ __launch_bounds__(256) void k_lat_gemm(
    const float* __restrict__ finalr, const float* __restrict__ Wf2l,
    float* __restrict__ lat) {
  __shared__ __align__(16) unsigned short As[64 * 32];
  __shared__ __align__(16) unsigned short Bs[64 * 32];
  const int rowBase = blockIdx.y * 64, colBase = blockIdx.x * 64;
  const int tid = threadIdx.x, wave = tid >> 6, lane = tid & 63;
  const int lm = lane & 15, lq = lane >> 4;
  const int sr = tid >> 2, sc = (tid & 3) * 8;
  f32x4 acc[4] = {};
  for (int k0 = 0; k0 < 2048; k0 += 32) {
    __syncthreads();
    stage8(&As[sr * 32 + sc], &finalr[(size_t)(rowBase + sr) * 2048 + k0 + sc]);
    int l = colBase + sr;
    if (l < LATENT) {
      stage8(&Bs[sr * 32 + sc], &Wf2l[(size_t)l * 2048 + k0 + sc]);
    } else {
      uint4 z = {0, 0, 0, 0};
      *(uint4*)&Bs[sr * 32 + sc] = z;
    }
    __syncthreads();
    bf16x8 af = *(const bf16x8*)&As[(wave * 16 + lm) * 32 + lq * 8];
#pragma unroll
    for (int j = 0; j < 4; ++j) {
      bf16x8 bfr = *(const bf16x8*)&Bs[(j * 16 + lm) * 32 + lq * 8];
      acc[j] = __builtin_amdgcn_mfma_f32_16x16x32_bf16(af, bfr, acc[j], 0, 0, 0);
    }
  }
#pragma unroll
  for (int j = 0; j < 4; ++j) {
    int col = colBase + j * 16 + lm;
    if (col < LATENT) {
#pragma unroll
      for (int r = 0; r < 4; ++r) {
        int row = rowBase + wave * 16 + lq * 4 + r;
        lat[row * LATENT + col] = acc[j][r];
      }
    }
  }
}

// ---------------------------------------------------------------------------
// output GEMM:
//   outLat[b,l] = lat[b,:101] . W_l2l[l,:101]           (output 1)
//   out[b,l]    = final[b,:2048].W_out[l,:] + scal * outLat[b,l]  (output 0)
// grid dim3(162, 8)
// ---------------------------------------------------------------------------
__global__ __launch_bounds__(256) void k_out_gemm(
    const float* __restrict__ finalr, const float* __restrict__ Wout,
    const float* __restrict__ lat, const float* __restrict__ Wl2l,
    const float* __restrict__ lscale, float* __restrict__ out,
    float* __restrict__ outLat) {
  __shared__ __align__(16) unsigned short As[64 * 32];
  __shared__ __align__(16) unsigned short Bs[64 * 32];
  const int rowBase = blockIdx.y * 64, colBase = blockIdx.x * 64;
  const int tid = threadIdx.x, wave = tid >> 6, lane = tid & 63;
  const int lm = lane & 15, lq = lane >> 4;
  const int sr = tid >> 2, sc = (tid & 3) * 8;
  const float scal = lscale[0];
  const int lrow = colBase + sr;
  const bool lvalid = (lrow < LL);
  f32x4 acc[4] = {};
  for (int k0 = 0; k0 < 2048; k0 += 32) {
    __syncthreads();
    stage8(&As[sr * 32 + sc], &finalr[(size_t)(rowBase + sr) * 2048 + k0 + sc]);
    if (lvalid) {
      stage8(&Bs[sr * 32 + sc], &Wout[(size_t)lrow * 2048 + k0 + sc]);
    } else {
      uint4 z = {0, 0, 0, 0};
      *(uint4*)&Bs[sr * 32 + sc] = z;
    }
    __syncthreads();
    bf16x8 af = *(const bf16x8*)&As[(wave * 16 + lm) * 32 + lq * 8];
#pragma unroll
    for (int j = 0; j < 4; ++j) {
      bf16x8 bfr = *(const bf16x8*)&Bs[(j * 16 + lm) * 32 + lq * 8];
      acc[j] = __builtin_amdgcn_mfma_f32_16x16x32_bf16(af, bfr, acc[j], 0, 0, 0);
    }
  }
  f32x4 acc2[4] = {};
  for (int k2 = 0; k2 < 128; k2 += 32) {
    __syncthreads();
    const int brow = rowBase + sr;
#pragma unroll
    for (int jj = 0; jj < 8; ++jj) {
      int idx = k2 + sc + jj;
      As[sr * 32 + sc + jj] = (idx < LATENT) ? f2bf(lat[brow * LATENT + idx]) : (unsigned short)0;
      Bs[sr * 32 + sc + jj] = (lvalid && idx < LATENT) ? f2bf(Wl2l[lrow * LATENT + idx]) : (unsigned short)0;
    }
    __syncthreads();
    bf16x8 af = *(const bf16x8*)&As[(wave * 16 + lm) * 32 + lq * 8];
#pragma unroll
    for (int j = 0; j < 4; ++j) {
      bf16x8 bfr = *(const bf16x8*)&Bs[(j * 16 + lm) * 32 + lq * 8];
      acc2[j] = __builtin_amdgcn_mfma_f32_16x16x32_bf16(af, bfr, acc2[j], 0, 0, 0);
    }
  }
#pragma unroll
  for (int j = 0; j < 4; ++j) {
    int col = colBase + j * 16 + lm;
    if (col < LL) {
#pragma unroll
      for (int r = 0; r < 4; ++r) {
        int row = rowBase + wave * 16 + lq * 4 + r;
        float lv = acc2[j][r];
        out[(size_t)row * LL + col] = acc[j][r] + scal * lv;
        outLat[(size_t)row * LL + col] = lv;
      }
    }
  }
}

// ======================= legacy fallback GEMMs (round-3, proven) ============
__global__ __launch_bounds__(256) void k_men_gemm(
    const float* __restrict__ X, const float* __restrict__ Wm,
    const float* __restrict__ wo, float* __restrict__ score) {
  __shared__ __align__(16) unsigned short As[64 * 32];
  __shared__ __align__(16) unsigned short Bs[64 * 32];
  const int bid = blockIdx.x;
  const int rowBase = (bid >> 4) * 64, colBase = (bid & 15) * 64;
  const int tid = threadIdx.x, wave = tid >> 6, lane = tid & 63;
  const int lm = lane & 15, lq = lane >> 4;
  const int sr = tid >> 2, sc = (tid & 3) * 8;
  f32x4 acc[4] = {};
  for (int k0 = 0; k0 < 1024; k0 += 32) {
    __syncthreads();
    stage8(&As[sr * 32 + sc], &X[(size_t)(rowBase + sr) * 1024 + k0 + sc]);
    stage8(&Bs[sr * 32 + sc], &Wm[(size_t)(colBase + sr) * 1024 + k0 + sc]);
    __syncthreads();
    bf16x8 af = *(const bf16x8*)&As[(wave * 16 + lm) * 32 + lq * 8];
#pragma unroll
    for (int j = 0; j < 4; ++j) {
      bf16x8 bfr = *(const bf16x8*)&Bs[(j * 16 + lm) * 32 + lq * 8];
      acc[j] = __builtin_amdgcn_mfma_f32_16x16x32_bf16(af, bfr, acc[j], 0, 0, 0);
    }
  }
  float rsum[4] = {0.f, 0.f, 0.f, 0.f};
#pragma unroll
  for (int j = 0; j < 4; ++j) {
    float w = wo[colBase + j * 16 + lm];
#pragma unroll
    for (int r = 0; r < 4; ++r) rsum[r] += tanhf(acc[j][r]) * w;
  }
#pragma unroll
  for (int m = 1; m <= 8; m <<= 1)
#pragma unroll
    for (int r = 0; r < 4; ++r) rsum[r] += __shfl_xor(rsum[r], m, 64);
  if (lm == 0) {
    int row0 = rowBase + wave * 16 + lq * 4;
#pragma unroll
    for (int r = 0; r < 4; ++r) atomicAdd(&score[row0 + r], rsum[r]);
  }
}

__global__ __launch_bounds__(256) void k_ctx_gemm(
    const float* __restrict__ X, const int* __restrict__ gathers,
    const float* __restrict__ Wc, const float* __restrict__ wd,
    const float* __restrict__ wo, const float* __restrict__ dist,
    const float* __restrict__ cb, float* __restrict__ score) {
  __shared__ __align__(16) unsigned short As[64 * 32];
  __shared__ __align__(16) unsigned short Bs[64 * 32];
  const int bid = blockIdx.x;
  const int rowBase = (bid >> 4) * 64, colBase = (bid & 15) * 64;
  const int tid = threadIdx.x, wave = tid >> 6, lane = tid & 63;
  const int lm = lane & 15, lq = lane >> 4;
  const int sr = tid >> 2, sc = (tid & 3) * 8;
  const int row_g = rowBase + sr;
  const int srcRow = (gathers[row_g >> 7] << 7) + (row_g & 127);
  f32x4 acc[4] = {};
  for (int k0 = 0; k0 < 1024; k0 += 32) {
    __syncthreads();
    stage8(&As[sr * 32 + sc], &X[(size_t)srcRow * 1024 + k0 + sc]);
    stage8(&Bs[sr * 32 + sc], &Wc[(size_t)(colBase + sr) * 1024 + k0 + sc]);
    __syncthreads();
    bf16x8 af = *(const bf16x8*)&As[(wave * 16 + lm) * 32 + lq * 8];
#pragma unroll
    for (int j = 0; j < 4; ++j) {
      bf16x8 bfr = *(const bf16x8*)&Bs[(j * 16 + lm) * 32 + lq * 8];
      acc[j] = __builtin_amdgcn_mfma_f32_16x16x32_bf16(af, bfr, acc[j], 0, 0, 0);
    }
  }
  float rsum[4] = {0.f, 0.f, 0.f, 0.f};
#pragma unroll
  for (int j = 0; j < 4; ++j) {
    int col = colBase + j * 16 + lm;
    float w = wo[col];
    float wdv = wd[col];
#pragma unroll
    for (int r = 0; r < 4; ++r) {
      int rg = rowBase + wave * 16 + lq * 4 + r;
      int b = rg >> 7, s = rg & 127;
      float v = acc[j][r] + cb[b * 1024 + col] + dist[b * 128 + s] * wdv;
      rsum[r] += tanhf(v) * w;
    }
  }
#pragma unroll
  for (int m = 1; m <= 8; m <<= 1)
#pragma unroll
    for (int r = 0; r < 4; ++r) rsum[r] += __shfl_xor(rsum[r], m, 64);
  if (lm == 0) {
    int row0 = rowBase + wave * 16 + lq * 4;
#pragma unroll
    for (int r = 0; r < 4; ++r) atomicAdd(&score[row0 + r], rsum[r]);
  }
}

extern "C" void kernel_launch(void* const* d_in, const int* in_sizes, int n_in,
                              void* d_out, int out_size, void* d_ws, size_t ws_size,
                              hipStream_t stream) {
  const float* X = (const float*)d_in[0];
  const float* men_mask = (const float*)d_in[1];
  const float* ctx_mask = (const float*)d_in[2];
  const float* dist = (const float*)d_in[3];
  const int* gathers = (const int*)d_in[4];
  const float* W_men_m = (const float*)d_in[5];
  const float* W_men_o = (const float*)d_in[6];
  const float* W_ctx_c = (const float*)d_in[7];
  const float* W_ctx_m = (const float*)d_in[8];
  const float* w_ctx_d = (const float*)d_in[9];
  const float* W_ctx_o = (const float*)d_in[10];
  const float* W_out = (const float*)d_in[11];
  const float* W_f2l = (const float*)d_in[12];
  const float* W_l2l = (const float*)d_in[13];
  const float* lscale = (const float*)d_in[14];
  float* out = (float*)d_out;
  float* outLat = out + (size_t)BB * LL;

  // byte-carved workspace
  size_t off = 0;
  auto carve = [&](size_t bytes) {
    void* p = (char*)d_ws + off;
    off = (off + bytes + 255) & ~(size_t)255;
    return p;
  };
  float* sent_score = (float*)carve(32768 * 4);
  float* ctx_score = (float*)carve(65536 * 4);
  float* finalr = (float*)carve((size_t)512 * 2048 * 4);
  float* cb = (float*)carve((size_t)512 * 1024 * 4);
  float* lat = (float*)carve((size_t)512 * LATENT * 4);
  unsigned short* Xb = (unsigned short*)carve((size_t)32768 * 1024 * 2);
  unsigned short* Wmb = (unsigned short*)carve((size_t)1024 * 1024 * 2);
  unsigned short* Wcb = (unsigned short*)carve((size_t)1024 * 1024 * 2);
  unsigned short* Hc = (unsigned short*)carve((size_t)32768 * 1024 * 2);
  const bool fits = off <= ws_size;

  if (fits) {
    hipMemsetAsync(sent_score, 0, 32768 * sizeof(float), stream);
    k_cvt<<<8192, 256, 0, stream>>>(X, Xb, 32768 * 1024 / 4);
    k_cvt<<<1024, 256, 0, stream>>>(W_men_m, Wmb, 1024 * 1024 / 4);
    k_cvt<<<1024, 256, 0, stream>>>(W_ctx_c, Wcb, 1024 * 1024 / 4);
    k_mc_gemm<<<dim3(16, 256), 256, 0, stream>>>(Xb, Wmb, Wcb, W_men_o, sent_score, Hc);
    k_soft<<<512, 256, 0, stream>>>(sent_score, men_mask, X, gathers, finalr, 0);
    k_cb_gemm<<<128, 256, 0, stream>>>(finalr, W_ctx_m, cb);
    k_ctx_score<<<512, 256, 0, stream>>>(Hc, gathers, cb, w_ctx_d, W_ctx_o, dist, ctx_score);
    k_soft<<<512, 256, 0, stream>>>(ctx_score, ctx_mask, X, gathers, finalr, 1);
    k_lat_gemm<<<dim3(2, 8), 256, 0, stream>>>(finalr, W_f2l, lat);
    k_out_gemm<<<dim3(162, 8), 256, 0, stream>>>(finalr, W_out, lat, W_l2l, lscale, out, outLat);
  } else {
    // legacy round-3 path (ws too small for dedup/bf16 staging buffers)
    hipMemsetAsync(d_ws, 0, (32768 + 65536) * sizeof(float), stream);
    k_men_gemm<<<8192, 256, 0, stream>>>(X, W_men_m, W_men_o, sent_score);
    k_soft<<<512, 256, 0, stream>>>(sent_score, men_mask, X, gathers, finalr, 0);
    k_cb_gemm<<<128, 256, 0, stream>>>(finalr, W_ctx_m, cb);
    k_ctx_gemm<<<16384, 256, 0, stream>>>(X, gathers, W_ctx_c, w_ctx_d, W_ctx_o, dist, cb, ctx_score);
    k_soft<<<512, 256, 0, stream>>>(ctx_score, ctx_mask, X, gathers, finalr, 1);
    k_lat_gemm<<<dim3(2, 8), 256, 0, stream>>>(finalr, W_f2l, lat);
    k_out_gemm<<<dim3(162, 8), 256, 0, stream>>>(finalr, W_out, lat, W_l2l, lscale, out, outLat);
  }
}

// Round 5
// 773.446 us; speedup vs baseline: 1.5167x; 1.2059x over previous
//
#include <hip/hip_runtime.h>
#include <hip/hip_bf16.h>

typedef __bf16 bf16x8 __attribute__((ext_vector_type(8)));
typedef float f32x4 __attribute__((ext_vector_type(4)));
typedef unsigned short u16x8 __attribute__((ext_vector_type(8)));

#define DEV __device__ __forceinline__

static constexpr int N_SENTC = 256, BB = 512, SS = 128, DD = 1024;
static constexpr int LL = 10331, LATENT = 101;
static constexpr int LPAD = 10368;  // 162*64, row-padded L
static constexpr int LATPAD = 128;  // padded latent

DEV float bf2f(unsigned short u) {
  unsigned v = (unsigned)u << 16;
  return __builtin_bit_cast(float, v);
}
DEV unsigned short f2bf(float f) {
  unsigned u = __builtin_bit_cast(unsigned, f);
  unsigned lsb = (u >> 16) & 1u;
  u += 0x7fffu + lsb;
  return (unsigned short)(u >> 16);
}

DEV void stage8(unsigned short* dst, const float* src) {
  float4 a = *(const float4*)src;
  float4 b = *(const float4*)(src + 4);
  unsigned short t[8];
  t[0] = f2bf(a.x); t[1] = f2bf(a.y); t[2] = f2bf(a.z); t[3] = f2bf(a.w);
  t[4] = f2bf(b.x); t[5] = f2bf(b.y); t[6] = f2bf(b.z); t[7] = f2bf(b.w);
  *(uint4*)dst = *(uint4*)t;
}

// async global->LDS, 16B per lane; lds base must be wave-uniform (HW adds lane*16)
DEV void gl_lds16(const unsigned short* g, unsigned short* l) {
  __builtin_amdgcn_global_load_lds(
      (const __attribute__((address_space(1))) unsigned int*)g,
      (__attribute__((address_space(3))) unsigned int*)l, 16, 0, 0);
}

// ---------------------------------------------------------------------------
// f32 -> bf16 bulk convert (n4 = count/4)
// ---------------------------------------------------------------------------
__global__ __launch_bounds__(256) void k_cvt(
    const float* __restrict__ src, unsigned short* __restrict__ dst, int n4) {
  for (int i = blockIdx.x * 256 + threadIdx.x; i < n4; i += gridDim.x * 256) {
    float4 v = ((const float4*)src)[i];
    unsigned short t[4] = {f2bf(v.x), f2bf(v.y), f2bf(v.z), f2bf(v.w)};
    ((uint2*)dst)[i] = *(const uint2*)t;
  }
}

// f32 [srcR,srcC] -> bf16 [dstR,dstC] zero-padded
__global__ __launch_bounds__(256) void k_cvt_pad(
    const float* __restrict__ src, unsigned short* __restrict__ dst,
    int srcR, int srcC, int dstC, int total) {
  for (int i = blockIdx.x * 256 + threadIdx.x; i < total; i += gridDim.x * 256) {
    int r = i / dstC, c = i - r * dstC;
    dst[i] = (r < srcR && c < srcC) ? f2bf(src[(size_t)r * srcC + c]) : (unsigned short)0;
  }
}

// ---------------------------------------------------------------------------
// Fused men-score + ctx-hidden GEMM (m97-style async staging).
// A = Xb [32768,1024] bf16. colTile<8: B=Wmb -> tanh*wo -> atomic men score.
// colTile>=8: B=Wcb -> Hc bf16. 128x128 tile, BK=32, LDS [128][32] unpadded,
// filled by global_load_lds dwordx4 (wave w covers rows [w*32,w*32+32)).
// grid = dim3(16, 256)
// ---------------------------------------------------------------------------
__global__ __launch_bounds__(256) void k_mc_gemm(
    const unsigned short* __restrict__ Xb, const unsigned short* __restrict__ Wmb,
    const unsigned short* __restrict__ Wcb, const float* __restrict__ wo,
    float* __restrict__ score, unsigned short* __restrict__ Hc) {
  __shared__ __align__(16) unsigned short As[128 * 32];
  __shared__ __align__(16) unsigned short Bs[128 * 32];
  const int colTile = blockIdx.x;
  const int rowBase = blockIdx.y * 128;
  const bool isMen = colTile < 8;
  const unsigned short* __restrict__ Bsrc = isMen ? Wmb : Wcb;
  const int bcolBase = (isMen ? colTile : colTile - 8) * 128;
  const int tid = threadIdx.x, wave = tid >> 6, lane = tid & 63;
  const int lm = lane & 15, lq = lane >> 4;
  const int wr = (wave & 1) * 64, wc = (wave >> 1) * 64;
  // staging geometry: LDS elem off = wave*1024 + issue*512 + lane*8
  //   -> row = wave*32 + issue*16 + lane/4, col = (lane&3)*8
  const int srow = wave * 32 + (lane >> 2);
  const int scol = (lane & 3) * 8;
  const unsigned short* aPtr = Xb + (size_t)(rowBase + srow) * 1024 + scol;
  const unsigned short* bPtr = Bsrc + (size_t)(bcolBase + srow) * 1024 + scol;
  unsigned short* aLds0 = As + wave * 1024;
  unsigned short* aLds1 = As + wave * 1024 + 512;
  unsigned short* bLds0 = Bs + wave * 1024;
  unsigned short* bLds1 = Bs + wave * 1024 + 512;
  f32x4 acc[4][4] = {};
  for (int k0 = 0; k0 < 1024; k0 += 32) {
    __syncthreads();
    gl_lds16(aPtr + k0, aLds0);
    gl_lds16(aPtr + k0 + 16 * 1024, aLds1);
    gl_lds16(bPtr + k0, bLds0);
    gl_lds16(bPtr + k0 + 16 * 1024, bLds1);
    __syncthreads();
    bf16x8 af[4], bfr[4];
#pragma unroll
    for (int m = 0; m < 4; ++m)
      af[m] = *(const bf16x8*)&As[(wr + m * 16 + lm) * 32 + lq * 8];
#pragma unroll
    for (int n = 0; n < 4; ++n)
      bfr[n] = *(const bf16x8*)&Bs[(wc + n * 16 + lm) * 32 + lq * 8];
#pragma unroll
    for (int m = 0; m < 4; ++m)
#pragma unroll
      for (int n = 0; n < 4; ++n)
        acc[m][n] = __builtin_amdgcn_mfma_f32_16x16x32_bf16(af[m], bfr[n], acc[m][n], 0, 0, 0);
  }
  if (isMen) {
    float wov[4];
#pragma unroll
    for (int n = 0; n < 4; ++n) wov[n] = wo[bcolBase + wc + n * 16 + lm];
    float rsum[4][4];
#pragma unroll
    for (int m = 0; m < 4; ++m)
#pragma unroll
      for (int r = 0; r < 4; ++r) {
        float s = 0.f;
#pragma unroll
        for (int n = 0; n < 4; ++n) s += tanhf(acc[m][n][r]) * wov[n];
        rsum[m][r] = s;
      }
#pragma unroll
    for (int msk = 1; msk <= 8; msk <<= 1)
#pragma unroll
      for (int m = 0; m < 4; ++m)
#pragma unroll
        for (int r = 0; r < 4; ++r) rsum[m][r] += __shfl_xor(rsum[m][r], msk, 64);
    if (lm == 0) {
#pragma unroll
      for (int m = 0; m < 4; ++m)
#pragma unroll
        for (int r = 0; r < 4; ++r)
          atomicAdd(&score[rowBase + wr + m * 16 + lq * 4 + r], rsum[m][r]);
    }
  } else {
#pragma unroll
    for (int m = 0; m < 4; ++m)
#pragma unroll
      for (int n = 0; n < 4; ++n) {
        int col = bcolBase + wc + n * 16 + lm;
#pragma unroll
        for (int r = 0; r < 4; ++r) {
          int row = rowBase + wr + m * 16 + lq * 4 + r;
          Hc[(size_t)row * 1024 + col] = f2bf(acc[m][n][r]);
        }
      }
  }
}

// ---------------------------------------------------------------------------
// ctx score from deduped hidden (unchanged from R4, proven)
// ---------------------------------------------------------------------------
__global__ __launch_bounds__(256) void k_ctx_score(
    const unsigned short* __restrict__ Hc, const int* __restrict__ gathers,
    const float* __restrict__ cb, const float* __restrict__ wd,
    const float* __restrict__ wo, const float* __restrict__ dist,
    float* __restrict__ score) {
  const int b = blockIdx.x, tid = threadIdx.x, wave = tid >> 6, lane = tid & 63;
  const int n = gathers[b];
  __shared__ float cbl[1024], wdl[1024], wol[1024];
  for (int i = tid; i < 1024; i += 256) {
    cbl[i] = cb[b * 1024 + i];
    wdl[i] = wd[i];
    wol[i] = wo[i];
  }
  __syncthreads();
  for (int s = wave; s < 128; s += 4) {
    float d = dist[b * 128 + s];
    const unsigned short* hrow = &Hc[(size_t)(n * 128 + s) * 1024 + lane * 16];
    unsigned short hs[16];
    *(uint4*)hs = *(const uint4*)hrow;
    *(uint4*)(hs + 8) = *(const uint4*)(hrow + 8);
    float p = 0.f;
#pragma unroll
    for (int j = 0; j < 16; ++j) {
      int e = lane * 16 + j;
      p += tanhf(bf2f(hs[j]) + cbl[e] + d * wdl[e]) * wol[e];
    }
#pragma unroll
    for (int msk = 1; msk <= 32; msk <<= 1) p += __shfl_xor(p, msk, 64);
    if (lane == 0) score[b * 128 + s] = p;
  }
}

// ---------------------------------------------------------------------------
// softmax over S=128 + weighted sum from bf16 X -> bf16 final_repr half.
// one block per b. Weighted sum: thread = (chunk c of 8 d's, s-half h),
// vec u16x8 loads, LDS combine, 16B stores.
// ---------------------------------------------------------------------------
__global__ __launch_bounds__(256) void k_softb(
    const float* __restrict__ score_src, const float* __restrict__ mask,
    const unsigned short* __restrict__ Xb, const int* __restrict__ gathers,
    unsigned short* __restrict__ finalrb, int isCtx) {
  const int b = blockIdx.x, tid = threadIdx.x;
  const int n = gathers[b];
  __shared__ float attn[128];
  __shared__ float red[128 * 8];
  __shared__ float smax, ssum;
  if (tid < 128) {
    int srow = isCtx ? b : n;
    attn[tid] = score_src[srow * 128 + tid] + (1.0f - mask[b * 128 + tid]) * (-10000.0f);
  }
  __syncthreads();
  if (tid == 0) {
    float m = attn[0];
    for (int i = 1; i < 128; ++i) m = fmaxf(m, attn[i]);
    smax = m;
  }
  __syncthreads();
  if (tid < 128) attn[tid] = expf(attn[tid] - smax);
  __syncthreads();
  if (tid == 0) {
    float s = 0.f;
    for (int i = 0; i < 128; ++i) s += attn[i];
    ssum = 1.0f / s;
  }
  __syncthreads();
  if (tid < 128) attn[tid] *= ssum;
  __syncthreads();
  const unsigned short* xb = Xb + (size_t)n * 128 * 1024;
  const int c = tid & 127, h = tid >> 7;
  float acc[8] = {};
  for (int s = h; s < 128; s += 2) {
    float w = attn[s];
    u16x8 v = *(const u16x8*)&xb[(size_t)s * 1024 + c * 8];
#pragma unroll
    for (int j = 0; j < 8; ++j) acc[j] += w * bf2f(v[j]);
  }
  if (h == 1) {
#pragma unroll
    for (int j = 0; j < 8; ++j) red[c * 8 + j] = acc[j];
  }
  __syncthreads();
  if (h == 0) {
    unsigned short o[8];
#pragma unroll
    for (int j = 0; j < 8; ++j) o[j] = f2bf(acc[j] + red[c * 8 + j]);
    *(uint4*)&finalrb[(size_t)b * 2048 + (isCtx ? 1024 : 0) + c * 8] = *(uint4*)o;
  }
}

// ---------------------------------------------------------------------------
// cb GEMM (bf16 in): cb[b,e] = men_repr[b,:1024] . Wcm[e,:]; grid 128
// ---------------------------------------------------------------------------
__global__ __launch_bounds__(256) void k_cb_gemm_b(
    const unsigned short* __restrict__ finalrb, const unsigned short* __restrict__ Wcmb,
    float* __restrict__ cb) {
  __shared__ __align__(16) unsigned short As[64 * 32];
  __shared__ __align__(16) unsigned short Bs[64 * 32];
  const int bid = blockIdx.x;
  const int rowBase = (bid >> 4) * 64, colBase = (bid & 15) * 64;
  const int tid = threadIdx.x, wave = tid >> 6, lane = tid & 63;
  const int lm = lane & 15, lq = lane >> 4;
  const int sr = tid >> 2, sc = (tid & 3) * 8;
  f32x4 acc[4] = {};
  for (int k0 = 0; k0 < 1024; k0 += 32) {
    __syncthreads();
    *(uint4*)&As[sr * 32 + sc] = *(const uint4*)&finalrb[(size_t)(rowBase + sr) * 2048 + k0 + sc];
    *(uint4*)&Bs[sr * 32 + sc] = *(const uint4*)&Wcmb[(size_t)(colBase + sr) * 1024 + k0 + sc];
    __syncthreads();
    bf16x8 af = *(const bf16x8*)&As[(wave * 16 + lm) * 32 + lq * 8];
#pragma unroll
    for (int j = 0; j < 4; ++j) {
      bf16x8 bfr = *(const bf16x8*)&Bs[(j * 16 + lm) * 32 + lq * 8];
      acc[j] = __builtin_amdgcn_mfma_f32_16x16x32_bf16(af, bfr, acc[j], 0, 0, 0);
    }
  }
#pragma unroll
  for (int j = 0; j < 4; ++j) {
    int col = colBase + j * 16 + lm;
#pragma unroll
    for (int r = 0; r < 4; ++r) {
      int row = rowBase + wave * 16 + lq * 4 + r;
      cb[row * 1024 + col] = acc[j][r];
    }
  }
}

// ---------------------------------------------------------------------------
// latent GEMM (bf16): latb[b,0:128] = finalrb[b,:2048] . Wf2lb[l,:2048]
// Wf2lb rows 101..127 are zero -> latb pad cols exactly 0. grid dim3(2,8)
// ---------------------------------------------------------------------------
__global__ __launch_bounds__(256) void k_lat_gemm_b(
    const unsigned short* __restrict__ finalrb, const unsigned short* __restrict__ Wf2lb,
    unsigned short* __restrict__ latb) {
  __shared__ __align__(16) unsigned short As[64 * 32];
  __shared__ __align__(16) unsigned short Bs[64 * 32];
  const int rowBase = blockIdx.y * 64, colBase = blockIdx.x * 64;
  const int tid = threadIdx.x, wave = tid >> 6, lane = tid & 63;
  const int lm = lane & 15, lq = lane >> 4;
  const int sr = tid >> 2, sc = (tid & 3) * 8;
  f32x4 acc[4] = {};
  for (int k0 = 0; k0 < 2048; k0 += 32) {
    __syncthreads();
    *(uint4*)&As[sr * 32 + sc] = *(const uint4*)&finalrb[(size_t)(rowBase + sr) * 2048 + k0 + sc];
    *(uint4*)&Bs[sr * 32 + sc] = *(const uint4*)&Wf2lb[(size_t)(colBase + sr) * 2048 + k0 + sc];
    __syncthreads();
    bf16x8 af = *(const bf16x8*)&As[(wave * 16 + lm) * 32 + lq * 8];
#pragma unroll
    for (int j = 0; j < 4; ++j) {
      bf16x8 bfr = *(const bf16x8*)&Bs[(j * 16 + lm) * 32 + lq * 8];
      acc[j] = __builtin_amdgcn_mfma_f32_16x16x32_bf16(af, bfr, acc[j], 0, 0, 0);
    }
  }
#pragma unroll
  for (int j = 0; j < 4; ++j) {
    int col = colBase + j * 16 + lm;
#pragma unroll
    for (int r = 0; r < 4; ++r) {
      int row = rowBase + wave * 16 + lq * 4 + r;
      latb[row * LATPAD + col] = f2bf(acc[j][r]);
    }
  }
}

// ---------------------------------------------------------------------------
// output GEMM (bf16 in): outLat = latb . Wl2lb^T; out = finalrb.Woutb^T + scal*outLat
// padded B rows -> no staging branches. grid dim3(162, 8)
// ---------------------------------------------------------------------------
__global__ __launch_bounds__(256) void k_out_gemm_b(
    const unsigned short* __restrict__ finalrb, const unsigned short* __restrict__ Woutb,
    const unsigned short* __restrict__ latb, const unsigned short* __restrict__ Wl2lb,
    const float* __restrict__ lscale, float* __restrict__ out,
    float* __restrict__ outLat) {
  __shared__ __align__(16) unsigned short As[64 * 32];
  __shared__ __align__(16) unsigned short Bs[64 * 32];
  const int rowBase = blockIdx.y * 64, colBase = blockIdx.x * 64;
  const int tid = threadIdx.x, wave = tid >> 6, lane = tid & 63;
  const int lm = lane & 15, lq = lane >> 4;
  const int sr = tid >> 2, sc = (tid & 3) * 8;
  const float scal = lscale[0];
  f32x4 acc[4] = {};
  for (int k0 = 0; k0 < 2048; k0 += 32) {
    __syncthreads();
    *(uint4*)&As[sr * 32 + sc] = *(const uint4*)&finalrb[(size_t)(rowBase + sr) * 2048 + k0 + sc];
    *(uint4*)&Bs[sr * 32 + sc] = *(const uint4*)&Woutb[(size_t)(colBase + sr) * 2048 + k0 + sc];
    __syncthreads();
    bf16x8 af = *(const bf16x8*)&As[(wave * 16 + lm) * 32 + lq * 8];
#pragma unroll
    for (int j = 0; j < 4; ++j) {
      bf16x8 bfr = *(const bf16x8*)&Bs[(j * 16 + lm) * 32 + lq * 8];
      acc[j] = __builtin_amdgcn_mfma_f32_16x16x32_bf16(af, bfr, acc[j], 0, 0, 0);
    }
  }
  f32x4 acc2[4] = {};
  for (int k2 = 0; k2 < 128; k2 += 32) {
    __syncthreads();
    *(uint4*)&As[sr * 32 + sc] = *(const uint4*)&latb[(size_t)(rowBase + sr) * LATPAD + k2 + sc];
    *(uint4*)&Bs[sr * 32 + sc] = *(const uint4*)&Wl2lb[(size_t)(colBase + sr) * LATPAD + k2 + sc];
    __syncthreads();
    bf16x8 af = *(const bf16x8*)&As[(wave * 16 + lm) * 32 + lq * 8];
#pragma unroll
    for (int j = 0; j < 4; ++j) {
      bf16x8 bfr = *(const bf16x8*)&Bs[(j * 16 + lm) * 32 + lq * 8];
      acc2[j] = __builtin_amdgcn_mfma_f32_16x16x32_bf16(af, bfr, acc2[j], 0, 0, 0);
    }
  }
#pragma unroll
  for (int j = 0; j < 4; ++j) {
    int col = colBase + j * 16 + lm;
    if (col < LL) {
#pragma unroll
      for (int r = 0; r < 4; ++r) {
        int row = rowBase + wave * 16 + lq * 4 + r;
        float lv = acc2[j][r];
        out[(size_t)row * LL + col] = acc[j][r] + scal * lv;
        outLat[(size_t)row * LL + col] = lv;
      }
    }
  }
}

// ======================= legacy fallback (round-3, proven) ==================
__global__ __launch_bounds__(256) void k_men_gemm(
    const float* __restrict__ X, const float* __restrict__ Wm,
    const float* __restrict__ wo, float* __restrict__ score) {
  __shared__ __align__(16) unsigned short As[64 * 32];
  __shared__ __align__(16) unsigned short Bs[64 * 32];
  const int bid = blockIdx.x;
  const int rowBase = (bid >> 4) * 64, colBase = (bid & 15) * 64;
  const int tid = threadIdx.x, wave = tid >> 6, lane = tid & 63;
  const int lm = lane & 15, lq = lane >> 4;
  const int sr = tid >> 2, sc = (tid & 3) * 8;
  f32x4 acc[4] = {};
  for (int k0 = 0; k0 < 1024; k0 += 32) {
    __syncthreads();
    stage8(&As[sr * 32 + sc], &X[(size_t)(rowBase + sr) * 1024 + k0 + sc]);
    stage8(&Bs[sr * 32 + sc], &Wm[(size_t)(colBase + sr) * 1024 + k0 + sc]);
    __syncthreads();
    bf16x8 af = *(const bf16x8*)&As[(wave * 16 + lm) * 32 + lq * 8];
#pragma unroll
    for (int j = 0; j < 4; ++j) {
      bf16x8 bfr = *(const bf16x8*)&Bs[(j * 16 + lm) * 32 + lq * 8];
      acc[j] = __builtin_amdgcn_mfma_f32_16x16x32_bf16(af, bfr, acc[j], 0, 0, 0);
    }
  }
  float rsum[4] = {0.f, 0.f, 0.f, 0.f};
#pragma unroll
  for (int j = 0; j < 4; ++j) {
    float w = wo[colBase + j * 16 + lm];
#pragma unroll
    for (int r = 0; r < 4; ++r) rsum[r] += tanhf(acc[j][r]) * w;
  }
#pragma unroll
  for (int m = 1; m <= 8; m <<= 1)
#pragma unroll
    for (int r = 0; r < 4; ++r) rsum[r] += __shfl_xor(rsum[r], m, 64);
  if (lm == 0) {
    int row0 = rowBase + wave * 16 + lq * 4;
#pragma unroll
    for (int r = 0; r < 4; ++r) atomicAdd(&score[row0 + r], rsum[r]);
  }
}

__global__ __launch_bounds__(256) void k_ctx_gemm(
    const float* __restrict__ X, const int* __restrict__ gathers,
    const float* __restrict__ Wc, const float* __restrict__ wd,
    const float* __restrict__ wo, const float* __restrict__ dist,
    const float* __restrict__ cb, float* __restrict__ score) {
  __shared__ __align__(16) unsigned short As[64 * 32];
  __shared__ __align__(16) unsigned short Bs[64 * 32];
  const int bid = blockIdx.x;
  const int rowBase = (bid >> 4) * 64, colBase = (bid & 15) * 64;
  const int tid = threadIdx.x, wave = tid >> 6, lane = tid & 63;
  const int lm = lane & 15, lq = lane >> 4;
  const int sr = tid >> 2, sc = (tid & 3) * 8;
  const int row_g = rowBase + sr;
  const int srcRow = (gathers[row_g >> 7] << 7) + (row_g & 127);
  f32x4 acc[4] = {};
  for (int k0 = 0; k0 < 1024; k0 += 32) {
    __syncthreads();
    stage8(&As[sr * 32 + sc], &X[(size_t)srcRow * 1024 + k0 + sc]);
    stage8(&Bs[sr * 32 + sc], &Wc[(size_t)(colBase + sr) * 1024 + k0 + sc]);
    __syncthreads();
    bf16x8 af = *(const bf16x8*)&As[(wave * 16 + lm) * 32 + lq * 8];
#pragma unroll
    for (int j = 0; j < 4; ++j) {
      bf16x8 bfr = *(const bf16x8*)&Bs[(j * 16 + lm) * 32 + lq * 8];
      acc[j] = __builtin_amdgcn_mfma_f32_16x16x32_bf16(af, bfr, acc[j], 0, 0, 0);
    }
  }
  float rsum[4] = {0.f, 0.f, 0.f, 0.f};
#pragma unroll
  for (int j = 0; j < 4; ++j) {
    int col = colBase + j * 16 + lm;
    float w = wo[col];
    float wdv = wd[col];
#pragma unroll
    for (int r = 0; r < 4; ++r) {
      int rg = rowBase + wave * 16 + lq * 4 + r;
      int b = rg >> 7, s = rg & 127;
      float v = acc[j][r] + cb[b * 1024 + col] + dist[b * 128 + s] * wdv;
      rsum[r] += tanhf(v) * w;
    }
  }
#pragma unroll
  for (int m = 1; m <= 8; m <<= 1)
#pragma unroll
    for (int r = 0; r < 4; ++r) rsum[r] += __shfl_xor(rsum[r], m, 64);
  if (lm == 0) {
    int row0 = rowBase + wave * 16 + lq * 4;
#pragma unroll
    for (int r = 0; r < 4; ++r) atomicAdd(&score[row0 + r], rsum[r]);
  }
}

__global__ __launch_bounds__(256) void k_soft(
    const float* __restrict__ score_src, const float* __restrict__ mask,
    const float* __restrict__ X, const int* __restrict__ gathers,
    float* __restrict__ finalr, int isCtx) {
  const int b = blockIdx.x, tid = threadIdx.x;
  const int n = gathers[b];
  __shared__ float attn[128];
  __shared__ float smax, ssum;
  if (tid < 128) {
    int srow = isCtx ? b : n;
    attn[tid] = score_src[srow * 128 + tid] + (1.0f - mask[b * 128 + tid]) * (-10000.0f);
  }
  __syncthreads();
  if (tid == 0) {
    float m = attn[0];
    for (int i = 1; i < 128; ++i) m = fmaxf(m, attn[i]);
    smax = m;
  }
  __syncthreads();
  if (tid < 128) attn[tid] = expf(attn[tid] - smax);
  __syncthreads();
  if (tid == 0) {
    float s = 0.f;
    for (int i = 0; i < 128; ++i) s += attn[i];
    ssum = 1.0f / s;
  }
  __syncthreads();
  if (tid < 128) attn[tid] *= ssum;
  __syncthreads();
  const float* xb = &X[(size_t)(n << 7) * 1024];
  const int off = isCtx ? 1024 : 0;
  for (int d = tid; d < 1024; d += 256) {
    float a = 0.f;
#pragma unroll 8
    for (int s = 0; s < 128; ++s) a += attn[s] * xb[s * 1024 + d];
    finalr[b * 2048 + off + d] = a;
  }
}

__global__ __launch_bounds__(256) void k_cb_gemm(
    const float* __restrict__ finalr, const float* __restrict__ Wcm,
    float* __restrict__ cb) {
  __shared__ __align__(16) unsigned short As[64 * 32];
  __shared__ __align__(16) unsigned short Bs[64 * 32];
  const int bid = blockIdx.x;
  const int rowBase = (bid >> 4) * 64, colBase = (bid & 15) * 64;
  const int tid = threadIdx.x, wave = tid >> 6, lane = tid & 63;
  const int lm = lane & 15, lq = lane >> 4;
  const int sr = tid >> 2, sc = (tid & 3) * 8;
  f32x4 acc[4] = {};
  for (int k0 = 0; k0 < 1024; k0 += 32) {
    __syncthreads();
    stage8(&As[sr * 32 + sc], &finalr[(size_t)(rowBase + sr) * 2048 + k0 + sc]);
    stage8(&Bs[sr * 32 + sc], &Wcm[(size_t)(colBase + sr) * 1024 + k0 + sc]);
    __syncthreads();
    bf16x8 af = *(const bf16x8*)&As[(wave * 16 + lm) * 32 + lq * 8];
#pragma unroll
    for (int j = 0; j < 4; ++j) {
      bf16x8 bfr = *(const bf16x8*)&Bs[(j * 16 + lm) * 32 + lq * 8];
      acc[j] = __builtin_amdgcn_mfma_f32_16x16x32_bf16(af, bfr, acc[j], 0, 0, 0);
    }
  }
#pragma unroll
  for (int j = 0; j < 4; ++j) {
    int col = colBase + j * 16 + lm;
#pragma unroll
    for (int r = 0; r < 4; ++r) {
      int row = rowBase + wave * 16 + lq * 4 + r;
      cb[row * 1024 + col] = acc[j][r];
    }
  }
}

__global__ __launch_bounds__(256) void k_lat_gemm(
    const float* __restrict__ finalr, const float* __restrict__ Wf2l,
    float* __restrict__ lat) {
  __shared__ __align__(16) unsigned short As[64 * 32];
  __shared__ __align__(16) unsigned short Bs[64 * 32];
  const int rowBase = blockIdx.y * 64, colBase = blockIdx.x * 64;
  const int tid = threadIdx.x, wave = tid >> 6, lane = tid & 63;
  const int lm = lane & 15, lq = lane >> 4;
  const int sr = tid >> 2, sc = (tid & 3) * 8;
  f32x4 acc[4] = {};
  for (int k0 = 0; k0 < 2048; k0 += 32) {
    __syncthreads();
    stage8(&As[sr * 32 + sc], &finalr[(size_t)(rowBase + sr) * 2048 + k0 + sc]);
    int l = colBase + sr;
    if (l < LATENT) {
      stage8(&Bs[sr * 32 + sc], &Wf2l[(size_t)l * 2048 + k0 + sc]);
    } else {
      uint4 z = {0, 0, 0, 0};
      *(uint4*)&Bs[sr * 32 + sc] = z;
    }
    __syncthreads();
    bf16x8 af = *(const bf16x8*)&As[(wave * 16 + lm) * 32 + lq * 8];
#pragma unroll
    for (int j = 0; j < 4; ++j) {
      bf16x8 bfr = *(const bf16x8*)&Bs[(j * 16 + lm) * 32 + lq * 8];
      acc[j] = __builtin_amdgcn_mfma_f32_16x16x32_bf16(af, bfr, acc[j], 0, 0, 0);
    }
  }
#pragma unroll
  for (int j = 0; j < 4; ++j) {
    int col = colBase + j * 16 + lm;
    if (col < LATENT) {
#pragma unroll
      for (int r = 0; r < 4; ++r) {
        int row = rowBase + wave * 16 + lq * 4 + r;
        lat[row * LATENT + col] = acc[j][r];
      }
    }
  }
}

__global__ __launch_bounds__(256) void k_out_gemm(
    const float* __restrict__ finalr, const float* __restrict__ Wout,
    const float* __restrict__ lat, const float* __restrict__ Wl2l,
    const float* __restrict__ lscale, float* __restrict__ out,
    float* __restrict__ outLat) {
  __shared__ __align__(16) unsigned short As[64 * 32];
  __shared__ __align__(16) unsigned short Bs[64 * 32];
  const int rowBase = blockIdx.y * 64, colBase = blockIdx.x * 64;
  const int tid = threadIdx.x, wave = tid >> 6, lane = tid & 63;
  const int lm = lane & 15, lq = lane >> 4;
  const int sr = tid >> 2, sc = (tid & 3) * 8;
  const float scal = lscale[0];
  const int lrow = colBase + sr;
  const bool lvalid = (lrow < LL);
  f32x4 acc[4] = {};
  for (int k0 = 0; k0 < 2048; k0 += 32) {
    __syncthreads();
    stage8(&As[sr * 32 + sc], &finalr[(size_t)(rowBase + sr) * 2048 + k0 + sc]);
    if (lvalid) {
      stage8(&Bs[sr * 32 + sc], &Wout[(size_t)lrow * 2048 + k0 + sc]);
    } else {
      uint4 z = {0, 0, 0, 0};
      *(uint4*)&Bs[sr * 32 + sc] = z;
    }
    __syncthreads();
    bf16x8 af = *(const bf16x8*)&As[(wave * 16 + lm) * 32 + lq * 8];
#pragma unroll
    for (int j = 0; j < 4; ++j) {
      bf16x8 bfr = *(const bf16x8*)&Bs[(j * 16 + lm) * 32 + lq * 8];
      acc[j] = __builtin_amdgcn_mfma_f32_16x16x32_bf16(af, bfr, acc[j], 0, 0, 0);
    }
  }
  f32x4 acc2[4] = {};
  for (int k2 = 0; k2 < 128; k2 += 32) {
    __syncthreads();
    const int brow = rowBase + sr;
#pragma unroll
    for (int jj = 0; jj < 8; ++jj) {
      int idx = k2 + sc + jj;
      As[sr * 32 + sc + jj] = (idx < LATENT) ? f2bf(lat[brow * LATENT + idx]) : (unsigned short)0;
      Bs[sr * 32 + sc + jj] = (lvalid && idx < LATENT) ? f2bf(Wl2l[lrow * LATENT + idx]) : (unsigned short)0;
    }
    __syncthreads();
    bf16x8 af = *(const bf16x8*)&As[(wave * 16 + lm) * 32 + lq * 8];
#pragma unroll
    for (int j = 0; j < 4; ++j) {
      bf16x8 bfr = *(const bf16x8*)&Bs[(j * 16 + lm) * 32 + lq * 8];
      acc2[j] = __builtin_amdgcn_mfma_f32_16x16x32_bf16(af, bfr, acc2[j], 0, 0, 0);
    }
  }
#pragma unroll
  for (int j = 0; j < 4; ++j) {
    int col = colBase + j * 16 + lm;
    if (col < LL) {
#pragma unroll
      for (int r = 0; r < 4; ++r) {
        int row = rowBase + wave * 16 + lq * 4 + r;
        float lv = acc2[j][r];
        out[(size_t)row * LL + col] = acc[j][r] + scal * lv;
        outLat[(size_t)row * LL + col] = lv;
      }
    }
  }
}

extern "C" void kernel_launch(void* const* d_in, const int* in_sizes, int n_in,
                              void* d_out, int out_size, void* d_ws, size_t ws_size,
                              hipStream_t stream) {
  const float* X = (const float*)d_in[0];
  const float* men_mask = (const float*)d_in[1];
  const float* ctx_mask = (const float*)d_in[2];
  const float* dist = (const float*)d_in[3];
  const int* gathers = (const int*)d_in[4];
  const float* W_men_m = (const float*)d_in[5];
  const float* W_men_o = (const float*)d_in[6];
  const float* W_ctx_c = (const float*)d_in[7];
  const float* W_ctx_m = (const float*)d_in[8];
  const float* w_ctx_d = (const float*)d_in[9];
  const float* W_ctx_o = (const float*)d_in[10];
  const float* W_out = (const float*)d_in[11];
  const float* W_f2l = (const float*)d_in[12];
  const float* W_l2l = (const float*)d_in[13];
  const float* lscale = (const float*)d_in[14];
  float* out = (float*)d_out;
  float* outLat = out + (size_t)BB * LL;

  size_t off = 0;
  auto carve = [&](size_t bytes) {
    void* p = (char*)d_ws + off;
    off = (off + bytes + 255) & ~(size_t)255;
    return p;
  };
  float* sent_score = (float*)carve(32768 * 4);
  float* ctx_score = (float*)carve(65536 * 4);
  float* finalr = (float*)carve((size_t)512 * 2048 * 4);        // legacy only
  float* cb = (float*)carve((size_t)512 * 1024 * 4);
  float* lat = (float*)carve((size_t)512 * LATENT * 4);         // legacy only
  unsigned short* Xb = (unsigned short*)carve((size_t)32768 * 1024 * 2);
  unsigned short* Wmb = (unsigned short*)carve((size_t)1024 * 1024 * 2);
  unsigned short* Wcb = (unsigned short*)carve((size_t)1024 * 1024 * 2);
  unsigned short* Wcmb = (unsigned short*)carve((size_t)1024 * 1024 * 2);
  unsigned short* Hc = (unsigned short*)carve((size_t)32768 * 1024 * 2);
  unsigned short* Wf2lb = (unsigned short*)carve((size_t)LATPAD * 2048 * 2);
  unsigned short* Wl2lb = (unsigned short*)carve((size_t)LPAD * LATPAD * 2);
  unsigned short* finalrb = (unsigned short*)carve((size_t)512 * 2048 * 2);
  unsigned short* latb = (unsigned short*)carve((size_t)512 * LATPAD * 2);
  const bool fits = off <= ws_size;
  // Woutb aliases Xb (Xb dead after ctx softmax; Woutb = 42.5 MB <= 67 MB)
  unsigned short* Woutb = Xb;

  if (fits) {
    hipMemsetAsync(sent_score, 0, 32768 * sizeof(float), stream);
    k_cvt<<<8192, 256, 0, stream>>>(X, Xb, 32768 * 1024 / 4);
    k_cvt<<<1024, 256, 0, stream>>>(W_men_m, Wmb, 1024 * 1024 / 4);
    k_cvt<<<1024, 256, 0, stream>>>(W_ctx_c, Wcb, 1024 * 1024 / 4);
    k_cvt<<<1024, 256, 0, stream>>>(W_ctx_m, Wcmb, 1024 * 1024 / 4);
    k_cvt<<<256, 256, 0, stream>>>(W_f2l, Wf2lb, LATENT * 2048 / 4);
    hipMemsetAsync(Wf2lb + (size_t)LATENT * 2048, 0,
                   (size_t)(LATPAD - LATENT) * 2048 * 2, stream);
    k_cvt_pad<<<1024, 256, 0, stream>>>(W_l2l, Wl2lb, LL, LATENT, LATPAD, LPAD * LATPAD);
    k_mc_gemm<<<dim3(16, 256), 256, 0, stream>>>(Xb, Wmb, Wcb, W_men_o, sent_score, Hc);
    k_softb<<<512, 256, 0, stream>>>(sent_score, men_mask, Xb, gathers, finalrb, 0);
    k_cb_gemm_b<<<128, 256, 0, stream>>>(finalrb, Wcmb, cb);
    k_ctx_score<<<512, 256, 0, stream>>>(Hc, gathers, cb, w_ctx_d, W_ctx_o, dist, ctx_score);
    k_softb<<<512, 256, 0, stream>>>(ctx_score, ctx_mask, Xb, gathers, finalrb, 1);
    k_lat_gemm_b<<<dim3(2, 8), 256, 0, stream>>>(finalrb, Wf2lb, latb);
    // Xb is dead now; convert W_out into its space
    k_cvt<<<8192, 256, 0, stream>>>(W_out, Woutb, LL * 2048 / 4);
    hipMemsetAsync(Woutb + (size_t)LL * 2048, 0,
                   (size_t)(LPAD - LL) * 2048 * 2, stream);
    k_out_gemm_b<<<dim3(162, 8), 256, 0, stream>>>(finalrb, Woutb, latb, Wl2lb,
                                                   lscale, out, outLat);
  } else {
    hipMemsetAsync(d_ws, 0, (32768 + 65536) * sizeof(float), stream);
    k_men_gemm<<<8192, 256, 0, stream>>>(X, W_men_m, W_men_o, sent_score);
    k_soft<<<512, 256, 0, stream>>>(sent_score, men_mask, X, gathers, finalr, 0);
    k_cb_gemm<<<128, 256, 0, stream>>>(finalr, W_ctx_m, cb);
    k_ctx_gemm<<<16384, 256, 0, stream>>>(X, gathers, W_ctx_c, w_ctx_d, W_ctx_o, dist, cb, ctx_score);
    k_soft<<<512, 256, 0, stream>>>(ctx_score, ctx_mask, X, gathers, finalr, 1);
    k_lat_gemm<<<dim3(2, 8), 256, 0, stream>>>(finalr, W_f2l, lat);
    k_out_gemm<<<dim3(162, 8), 256, 0, stream>>>(finalr, W_out, lat, W_l2l, lscale, out, outLat);
  }
}

// Round 6
// 740.913 us; speedup vs baseline: 1.5833x; 1.0439x over previous
//
#include <hip/hip_runtime.h>
#include <hip/hip_bf16.h>

typedef __bf16 bf16x8 __attribute__((ext_vector_type(8)));
typedef float f32x4 __attribute__((ext_vector_type(4)));
typedef unsigned short u16x8 __attribute__((ext_vector_type(8)));

#define DEV __device__ __forceinline__

static constexpr int N_SENTC = 256, BB = 512, SS = 128, DD = 1024;
static constexpr int LL = 10331, LATENT = 101;
static constexpr int LPAD = 10368;  // 162*64 = 81*128, row-padded L
static constexpr int LATPAD = 128;  // padded latent

DEV float bf2f(unsigned short u) {
  unsigned v = (unsigned)u << 16;
  return __builtin_bit_cast(float, v);
}
DEV unsigned short f2bf(float f) {
  unsigned u = __builtin_bit_cast(unsigned, f);
  unsigned lsb = (u >> 16) & 1u;
  u += 0x7fffu + lsb;
  return (unsigned short)(u >> 16);
}

DEV void stage8(unsigned short* dst, const float* src) {
  float4 a = *(const float4*)src;
  float4 b = *(const float4*)(src + 4);
  unsigned short t[8];
  t[0] = f2bf(a.x); t[1] = f2bf(a.y); t[2] = f2bf(a.z); t[3] = f2bf(a.w);
  t[4] = f2bf(b.x); t[5] = f2bf(b.y); t[6] = f2bf(b.z); t[7] = f2bf(b.w);
  *(uint4*)dst = *(uint4*)t;
}

// async global->LDS, 16B per lane; lds base wave-uniform (HW adds lane*16)
DEV void gl_lds16(const unsigned short* g, unsigned short* l) {
  __builtin_amdgcn_global_load_lds(
      (const __attribute__((address_space(1))) unsigned int*)g,
      (__attribute__((address_space(3))) unsigned int*)l, 16, 0, 0);
}

// ---------------------------------------------------------------------------
// f32 -> bf16 bulk convert (n4 = count/4)
// ---------------------------------------------------------------------------
__global__ __launch_bounds__(256) void k_cvt(
    const float* __restrict__ src, unsigned short* __restrict__ dst, int n4) {
  for (int i = blockIdx.x * 256 + threadIdx.x; i < n4; i += gridDim.x * 256) {
    float4 v = ((const float4*)src)[i];
    unsigned short t[4] = {f2bf(v.x), f2bf(v.y), f2bf(v.z), f2bf(v.w)};
    ((uint2*)dst)[i] = *(const uint2*)t;
  }
}

// f32 [srcR,srcC] -> bf16 [dstR,dstC] zero-padded
__global__ __launch_bounds__(256) void k_cvt_pad(
    const float* __restrict__ src, unsigned short* __restrict__ dst,
    int srcR, int srcC, int dstC, int total) {
  for (int i = blockIdx.x * 256 + threadIdx.x; i < total; i += gridDim.x * 256) {
    int r = i / dstC, c = i - r * dstC;
    dst[i] = (r < srcR && c < srcC) ? f2bf(src[(size_t)r * srcC + c]) : (unsigned short)0;
  }
}

// ---------------------------------------------------------------------------
// Fused men-score + ctx-hidden GEMM. BK=64 as two sequential [128][32]
// sub-tiles (DMA-contiguous, same bank behavior as BK=32): per K-iter
// 8 DMA issues, 16 ds_read_b128, 32 MFMA per wave -> half the barrier drains.
// grid = dim3(16, 256)
// ---------------------------------------------------------------------------
__global__ __launch_bounds__(256) void k_mc_gemm(
    const unsigned short* __restrict__ Xb, const unsigned short* __restrict__ Wmb,
    const unsigned short* __restrict__ Wcb, const float* __restrict__ wo,
    float* __restrict__ score, unsigned short* __restrict__ Hc) {
  __shared__ __align__(16) unsigned short As[2 * 128 * 32];
  __shared__ __align__(16) unsigned short Bs[2 * 128 * 32];
  const int colTile = blockIdx.x;
  const int rowBase = blockIdx.y * 128;
  const bool isMen = colTile < 8;
  const unsigned short* __restrict__ Bsrc = isMen ? Wmb : Wcb;
  const int bcolBase = (isMen ? colTile : colTile - 8) * 128;
  const int tid = threadIdx.x, wave = tid >> 6, lane = tid & 63;
  const int lm = lane & 15, lq = lane >> 4;
  const int wr = (wave & 1) * 64, wc = (wave >> 1) * 64;
  // staging: wave w covers rows [w*32, w*32+32) per sub-tile, 2 issues each
  const int srow = wave * 32 + (lane >> 2);
  const int scol = (lane & 3) * 8;
  const unsigned short* aPtr = Xb + (size_t)(rowBase + srow) * 1024 + scol;
  const unsigned short* bPtr = Bsrc + (size_t)(bcolBase + srow) * 1024 + scol;
  f32x4 acc[4][4] = {};
  for (int k0 = 0; k0 < 1024; k0 += 64) {
    __syncthreads();
#pragma unroll
    for (int h = 0; h < 2; ++h) {
      gl_lds16(aPtr + k0 + h * 32, As + h * 4096 + wave * 1024);
      gl_lds16(aPtr + k0 + h * 32 + 16 * 1024, As + h * 4096 + wave * 1024 + 512);
      gl_lds16(bPtr + k0 + h * 32, Bs + h * 4096 + wave * 1024);
      gl_lds16(bPtr + k0 + h * 32 + 16 * 1024, Bs + h * 4096 + wave * 1024 + 512);
    }
    __syncthreads();
#pragma unroll
    for (int h = 0; h < 2; ++h) {
      bf16x8 af[4], bfr[4];
#pragma unroll
      for (int m = 0; m < 4; ++m)
        af[m] = *(const bf16x8*)&As[h * 4096 + (wr + m * 16 + lm) * 32 + lq * 8];
#pragma unroll
      for (int n = 0; n < 4; ++n)
        bfr[n] = *(const bf16x8*)&Bs[h * 4096 + (wc + n * 16 + lm) * 32 + lq * 8];
#pragma unroll
      for (int m = 0; m < 4; ++m)
#pragma unroll
        for (int n = 0; n < 4; ++n)
          acc[m][n] = __builtin_amdgcn_mfma_f32_16x16x32_bf16(af[m], bfr[n], acc[m][n], 0, 0, 0);
    }
  }
  if (isMen) {
    float wov[4];
#pragma unroll
    for (int n = 0; n < 4; ++n) wov[n] = wo[bcolBase + wc + n * 16 + lm];
    float rsum[4][4];
#pragma unroll
    for (int m = 0; m < 4; ++m)
#pragma unroll
      for (int r = 0; r < 4; ++r) {
        float s = 0.f;
#pragma unroll
        for (int n = 0; n < 4; ++n) s += tanhf(acc[m][n][r]) * wov[n];
        rsum[m][r] = s;
      }
#pragma unroll
    for (int msk = 1; msk <= 8; msk <<= 1)
#pragma unroll
      for (int m = 0; m < 4; ++m)
#pragma unroll
        for (int r = 0; r < 4; ++r) rsum[m][r] += __shfl_xor(rsum[m][r], msk, 64);
    if (lm == 0) {
#pragma unroll
      for (int m = 0; m < 4; ++m)
#pragma unroll
        for (int r = 0; r < 4; ++r)
          atomicAdd(&score[rowBase + wr + m * 16 + lq * 4 + r], rsum[m][r]);
    }
  } else {
#pragma unroll
    for (int m = 0; m < 4; ++m)
#pragma unroll
      for (int n = 0; n < 4; ++n) {
        int col = bcolBase + wc + n * 16 + lm;
#pragma unroll
        for (int r = 0; r < 4; ++r) {
          int row = rowBase + wr + m * 16 + lq * 4 + r;
          Hc[(size_t)row * 1024 + col] = f2bf(acc[m][n][r]);
        }
      }
  }
}

// ---------------------------------------------------------------------------
// ctx score from deduped hidden (proven)
// ---------------------------------------------------------------------------
__global__ __launch_bounds__(256) void k_ctx_score(
    const unsigned short* __restrict__ Hc, const int* __restrict__ gathers,
    const float* __restrict__ cb, const float* __restrict__ wd,
    const float* __restrict__ wo, const float* __restrict__ dist,
    float* __restrict__ score) {
  const int b = blockIdx.x, tid = threadIdx.x, wave = tid >> 6, lane = tid & 63;
  const int n = gathers[b];
  __shared__ float cbl[1024], wdl[1024], wol[1024];
  for (int i = tid; i < 1024; i += 256) {
    cbl[i] = cb[b * 1024 + i];
    wdl[i] = wd[i];
    wol[i] = wo[i];
  }
  __syncthreads();
  for (int s = wave; s < 128; s += 4) {
    float d = dist[b * 128 + s];
    const unsigned short* hrow = &Hc[(size_t)(n * 128 + s) * 1024 + lane * 16];
    unsigned short hs[16];
    *(uint4*)hs = *(const uint4*)hrow;
    *(uint4*)(hs + 8) = *(const uint4*)(hrow + 8);
    float p = 0.f;
#pragma unroll
    for (int j = 0; j < 16; ++j) {
      int e = lane * 16 + j;
      p += tanhf(bf2f(hs[j]) + cbl[e] + d * wdl[e]) * wol[e];
    }
#pragma unroll
    for (int msk = 1; msk <= 32; msk <<= 1) p += __shfl_xor(p, msk, 64);
    if (lane == 0) score[b * 128 + s] = p;
  }
}

// ---------------------------------------------------------------------------
// softmax over S=128 + weighted sum from bf16 X -> bf16 final_repr half.
// ---------------------------------------------------------------------------
__global__ __launch_bounds__(256) void k_softb(
    const float* __restrict__ score_src, const float* __restrict__ mask,
    const unsigned short* __restrict__ Xb, const int* __restrict__ gathers,
    unsigned short* __restrict__ finalrb, int isCtx) {
  const int b = blockIdx.x, tid = threadIdx.x;
  const int n = gathers[b];
  __shared__ float attn[128];
  __shared__ float red[128 * 8];
  __shared__ float smax, ssum;
  if (tid < 128) {
    int srow = isCtx ? b : n;
    attn[tid] = score_src[srow * 128 + tid] + (1.0f - mask[b * 128 + tid]) * (-10000.0f);
  }
  __syncthreads();
  if (tid == 0) {
    float m = attn[0];
    for (int i = 1; i < 128; ++i) m = fmaxf(m, attn[i]);
    smax = m;
  }
  __syncthreads();
  if (tid < 128) attn[tid] = expf(attn[tid] - smax);
  __syncthreads();
  if (tid == 0) {
    float s = 0.f;
    for (int i = 0; i < 128; ++i) s += attn[i];
    ssum = 1.0f / s;
  }
  __syncthreads();
  if (tid < 128) attn[tid] *= ssum;
  __syncthreads();
  const unsigned short* xb = Xb + (size_t)n * 128 * 1024;
  const int c = tid & 127, h = tid >> 7;
  float acc[8] = {};
  for (int s = h; s < 128; s += 2) {
    float w = attn[s];
    u16x8 v = *(const u16x8*)&xb[(size_t)s * 1024 + c * 8];
#pragma unroll
    for (int j = 0; j < 8; ++j) acc[j] += w * bf2f(v[j]);
  }
  if (h == 1) {
#pragma unroll
    for (int j = 0; j < 8; ++j) red[c * 8 + j] = acc[j];
  }
  __syncthreads();
  if (h == 0) {
    unsigned short o[8];
#pragma unroll
    for (int j = 0; j < 8; ++j) o[j] = f2bf(acc[j] + red[c * 8 + j]);
    *(uint4*)&finalrb[(size_t)b * 2048 + (isCtx ? 1024 : 0) + c * 8] = *(uint4*)o;
  }
}

// ---------------------------------------------------------------------------
// cb GEMM (bf16 in): cb[b,e] = men_repr[b,:1024] . Wcm[e,:]; grid 128
// ---------------------------------------------------------------------------
__global__ __launch_bounds__(256) void k_cb_gemm_b(
    const unsigned short* __restrict__ finalrb, const unsigned short* __restrict__ Wcmb,
    float* __restrict__ cb) {
  __shared__ __align__(16) unsigned short As[64 * 32];
  __shared__ __align__(16) unsigned short Bs[64 * 32];
  const int bid = blockIdx.x;
  const int rowBase = (bid >> 4) * 64, colBase = (bid & 15) * 64;
  const int tid = threadIdx.x, wave = tid >> 6, lane = tid & 63;
  const int lm = lane & 15, lq = lane >> 4;
  const int sr = tid >> 2, sc = (tid & 3) * 8;
  f32x4 acc[4] = {};
  for (int k0 = 0; k0 < 1024; k0 += 32) {
    __syncthreads();
    *(uint4*)&As[sr * 32 + sc] = *(const uint4*)&finalrb[(size_t)(rowBase + sr) * 2048 + k0 + sc];
    *(uint4*)&Bs[sr * 32 + sc] = *(const uint4*)&Wcmb[(size_t)(colBase + sr) * 1024 + k0 + sc];
    __syncthreads();
    bf16x8 af = *(const bf16x8*)&As[(wave * 16 + lm) * 32 + lq * 8];
#pragma unroll
    for (int j = 0; j < 4; ++j) {
      bf16x8 bfr = *(const bf16x8*)&Bs[(j * 16 + lm) * 32 + lq * 8];
      acc[j] = __builtin_amdgcn_mfma_f32_16x16x32_bf16(af, bfr, acc[j], 0, 0, 0);
    }
  }
#pragma unroll
  for (int j = 0; j < 4; ++j) {
    int col = colBase + j * 16 + lm;
#pragma unroll
    for (int r = 0; r < 4; ++r) {
      int row = rowBase + wave * 16 + lq * 4 + r;
      cb[row * 1024 + col] = acc[j][r];
    }
  }
}

// ---------------------------------------------------------------------------
// latent GEMM (bf16): latb[b,0:128] = finalrb . Wf2lb^T; grid dim3(2,8)
// ---------------------------------------------------------------------------
__global__ __launch_bounds__(256) void k_lat_gemm_b(
    const unsigned short* __restrict__ finalrb, const unsigned short* __restrict__ Wf2lb,
    unsigned short* __restrict__ latb) {
  __shared__ __align__(16) unsigned short As[64 * 32];
  __shared__ __align__(16) unsigned short Bs[64 * 32];
  const int rowBase = blockIdx.y * 64, colBase = blockIdx.x * 64;
  const int tid = threadIdx.x, wave = tid >> 6, lane = tid & 63;
  const int lm = lane & 15, lq = lane >> 4;
  const int sr = tid >> 2, sc = (tid & 3) * 8;
  f32x4 acc[4] = {};
  for (int k0 = 0; k0 < 2048; k0 += 32) {
    __syncthreads();
    *(uint4*)&As[sr * 32 + sc] = *(const uint4*)&finalrb[(size_t)(rowBase + sr) * 2048 + k0 + sc];
    *(uint4*)&Bs[sr * 32 + sc] = *(const uint4*)&Wf2lb[(size_t)(colBase + sr) * 2048 + k0 + sc];
    __syncthreads();
    bf16x8 af = *(const bf16x8*)&As[(wave * 16 + lm) * 32 + lq * 8];
#pragma unroll
    for (int j = 0; j < 4; ++j) {
      bf16x8 bfr = *(const bf16x8*)&Bs[(j * 16 + lm) * 32 + lq * 8];
      acc[j] = __builtin_amdgcn_mfma_f32_16x16x32_bf16(af, bfr, acc[j], 0, 0, 0);
    }
  }
#pragma unroll
  for (int j = 0; j < 4; ++j) {
    int col = colBase + j * 16 + lm;
#pragma unroll
    for (int r = 0; r < 4; ++r) {
      int row = rowBase + wave * 16 + lq * 4 + r;
      latb[row * LATPAD + col] = f2bf(acc[j][r]);
    }
  }
}

// ---------------------------------------------------------------------------
// output GEMM, 128x128 async BK=64 structure:
//   acc  = finalrb[128,2048] . Woutb[128cols,2048]^T
//   acc2 = latb[128,128] . Wl2lb[128cols,128]^T
//   out = acc + scal*acc2 ; outLat = acc2. grid dim3(81, 4) - all co-resident
// ---------------------------------------------------------------------------
__global__ __launch_bounds__(256) void k_out_gemm_b(
    const unsigned short* __restrict__ finalrb, const unsigned short* __restrict__ Woutb,
    const unsigned short* __restrict__ latb, const unsigned short* __restrict__ Wl2lb,
    const float* __restrict__ lscale, float* __restrict__ out,
    float* __restrict__ outLat) {
  __shared__ __align__(16) unsigned short As[2 * 128 * 32];
  __shared__ __align__(16) unsigned short Bs[2 * 128 * 32];
  const int colBase = blockIdx.x * 128;
  const int rowBase = blockIdx.y * 128;
  const int tid = threadIdx.x, wave = tid >> 6, lane = tid & 63;
  const int lm = lane & 15, lq = lane >> 4;
  const int wr = (wave & 1) * 64, wc = (wave >> 1) * 64;
  const int srow = wave * 32 + (lane >> 2);
  const int scol = (lane & 3) * 8;
  const float scal = lscale[0];
  const unsigned short* aPtr = finalrb + (size_t)(rowBase + srow) * 2048 + scol;
  const unsigned short* bPtr = Woutb + (size_t)(colBase + srow) * 2048 + scol;
  f32x4 acc[4][4] = {};
  for (int k0 = 0; k0 < 2048; k0 += 64) {
    __syncthreads();
#pragma unroll
    for (int h = 0; h < 2; ++h) {
      gl_lds16(aPtr + k0 + h * 32, As + h * 4096 + wave * 1024);
      gl_lds16(aPtr + k0 + h * 32 + 16 * 2048, As + h * 4096 + wave * 1024 + 512);
      gl_lds16(bPtr + k0 + h * 32, Bs + h * 4096 + wave * 1024);
      gl_lds16(bPtr + k0 + h * 32 + 16 * 2048, Bs + h * 4096 + wave * 1024 + 512);
    }
    __syncthreads();
#pragma unroll
    for (int h = 0; h < 2; ++h) {
      bf16x8 af[4], bfr[4];
#pragma unroll
      for (int m = 0; m < 4; ++m)
        af[m] = *(const bf16x8*)&As[h * 4096 + (wr + m * 16 + lm) * 32 + lq * 8];
#pragma unroll
      for (int n = 0; n < 4; ++n)
        bfr[n] = *(const bf16x8*)&Bs[h * 4096 + (wc + n * 16 + lm) * 32 + lq * 8];
#pragma unroll
      for (int m = 0; m < 4; ++m)
#pragma unroll
        for (int n = 0; n < 4; ++n)
          acc[m][n] = __builtin_amdgcn_mfma_f32_16x16x32_bf16(af[m], bfr[n], acc[m][n], 0, 0, 0);
    }
  }
  // latent phase: K=128 (2 iters), separate accumulator
  const unsigned short* aPtr2 = latb + (size_t)(rowBase + srow) * LATPAD + scol;
  const unsigned short* bPtr2 = Wl2lb + (size_t)(colBase + srow) * LATPAD + scol;
  f32x4 acc2[4][4] = {};
  for (int k0 = 0; k0 < 128; k0 += 64) {
    __syncthreads();
#pragma unroll
    for (int h = 0; h < 2; ++h) {
      gl_lds16(aPtr2 + k0 + h * 32, As + h * 4096 + wave * 1024);
      gl_lds16(aPtr2 + k0 + h * 32 + 16 * LATPAD, As + h * 4096 + wave * 1024 + 512);
      gl_lds16(bPtr2 + k0 + h * 32, Bs + h * 4096 + wave * 1024);
      gl_lds16(bPtr2 + k0 + h * 32 + 16 * LATPAD, Bs + h * 4096 + wave * 1024 + 512);
    }
    __syncthreads();
#pragma unroll
    for (int h = 0; h < 2; ++h) {
      bf16x8 af[4], bfr[4];
#pragma unroll
      for (int m = 0; m < 4; ++m)
        af[m] = *(const bf16x8*)&As[h * 4096 + (wr + m * 16 + lm) * 32 + lq * 8];
#pragma unroll
      for (int n = 0; n < 4; ++n)
        bfr[n] = *(const bf16x8*)&Bs[h * 4096 + (wc + n * 16 + lm) * 32 + lq * 8];
#pragma unroll
      for (int m = 0; m < 4; ++m)
#pragma unroll
        for (int n = 0; n < 4; ++n)
          acc2[m][n] = __builtin_amdgcn_mfma_f32_16x16x32_bf16(af[m], bfr[n], acc2[m][n], 0, 0, 0);
    }
  }
#pragma unroll
  for (int m = 0; m < 4; ++m)
#pragma unroll
    for (int n = 0; n < 4; ++n) {
      int col = colBase + wc + n * 16 + lm;
      if (col < LL) {
#pragma unroll
        for (int r = 0; r < 4; ++r) {
          int row = rowBase + wr + m * 16 + lq * 4 + r;
          float lv = acc2[m][n][r];
          out[(size_t)row * LL + col] = acc[m][n][r] + scal * lv;
          outLat[(size_t)row * LL + col] = lv;
        }
      }
    }
}

// ======================= legacy fallback (round-3, proven) ==================
__global__ __launch_bounds__(256) void k_men_gemm(
    const float* __restrict__ X, const float* __restrict__ Wm,
    const float* __restrict__ wo, float* __restrict__ score) {
  __shared__ __align__(16) unsigned short As[64 * 32];
  __shared__ __align__(16) unsigned short Bs[64 * 32];
  const int bid = blockIdx.x;
  const int rowBase = (bid >> 4) * 64, colBase = (bid & 15) * 64;
  const int tid = threadIdx.x, wave = tid >> 6, lane = tid & 63;
  const int lm = lane & 15, lq = lane >> 4;
  const int sr = tid >> 2, sc = (tid & 3) * 8;
  f32x4 acc[4] = {};
  for (int k0 = 0; k0 < 1024; k0 += 32) {
    __syncthreads();
    stage8(&As[sr * 32 + sc], &X[(size_t)(rowBase + sr) * 1024 + k0 + sc]);
    stage8(&Bs[sr * 32 + sc], &Wm[(size_t)(colBase + sr) * 1024 + k0 + sc]);
    __syncthreads();
    bf16x8 af = *(const bf16x8*)&As[(wave * 16 + lm) * 32 + lq * 8];
#pragma unroll
    for (int j = 0; j < 4; ++j) {
      bf16x8 bfr = *(const bf16x8*)&Bs[(j * 16 + lm) * 32 + lq * 8];
      acc[j] = __builtin_amdgcn_mfma_f32_16x16x32_bf16(af, bfr, acc[j], 0, 0, 0);
    }
  }
  float rsum[4] = {0.f, 0.f, 0.f, 0.f};
#pragma unroll
  for (int j = 0; j < 4; ++j) {
    float w = wo[colBase + j * 16 + lm];
#pragma unroll
    for (int r = 0; r < 4; ++r) rsum[r] += tanhf(acc[j][r]) * w;
  }
#pragma unroll
  for (int m = 1; m <= 8; m <<= 1)
#pragma unroll
    for (int r = 0; r < 4; ++r) rsum[r] += __shfl_xor(rsum[r], m, 64);
  if (lm == 0) {
    int row0 = rowBase + wave * 16 + lq * 4;
#pragma unroll
    for (int r = 0; r < 4; ++r) atomicAdd(&score[row0 + r], rsum[r]);
  }
}

__global__ __launch_bounds__(256) void k_ctx_gemm(
    const float* __restrict__ X, const int* __restrict__ gathers,
    const float* __restrict__ Wc, const float* __restrict__ wd,
    const float* __restrict__ wo, const float* __restrict__ dist,
    const float* __restrict__ cb, float* __restrict__ score) {
  __shared__ __align__(16) unsigned short As[64 * 32];
  __shared__ __align__(16) unsigned short Bs[64 * 32];
  const int bid = blockIdx.x;
  const int rowBase = (bid >> 4) * 64, colBase = (bid & 15) * 64;
  const int tid = threadIdx.x, wave = tid >> 6, lane = tid & 63;
  const int lm = lane & 15, lq = lane >> 4;
  const int sr = tid >> 2, sc = (tid & 3) * 8;
  const int row_g = rowBase + sr;
  const int srcRow = (gathers[row_g >> 7] << 7) + (row_g & 127);
  f32x4 acc[4] = {};
  for (int k0 = 0; k0 < 1024; k0 += 32) {
    __syncthreads();
    stage8(&As[sr * 32 + sc], &X[(size_t)srcRow * 1024 + k0 + sc]);
    stage8(&Bs[sr * 32 + sc], &Wc[(size_t)(colBase + sr) * 1024 + k0 + sc]);
    __syncthreads();
    bf16x8 af = *(const bf16x8*)&As[(wave * 16 + lm) * 32 + lq * 8];
#pragma unroll
    for (int j = 0; j < 4; ++j) {
      bf16x8 bfr = *(const bf16x8*)&Bs[(j * 16 + lm) * 32 + lq * 8];
      acc[j] = __builtin_amdgcn_mfma_f32_16x16x32_bf16(af, bfr, acc[j], 0, 0, 0);
    }
  }
  float rsum[4] = {0.f, 0.f, 0.f, 0.f};
#pragma unroll
  for (int j = 0; j < 4; ++j) {
    int col = colBase + j * 16 + lm;
    float w = wo[col];
    float wdv = wd[col];
#pragma unroll
    for (int r = 0; r < 4; ++r) {
      int rg = rowBase + wave * 16 + lq * 4 + r;
      int b = rg >> 7, s = rg & 127;
      float v = acc[j][r] + cb[b * 1024 + col] + dist[b * 128 + s] * wdv;
      rsum[r] += tanhf(v) * w;
    }
  }
#pragma unroll
  for (int m = 1; m <= 8; m <<= 1)
#pragma unroll
    for (int r = 0; r < 4; ++r) rsum[r] += __shfl_xor(rsum[r], m, 64);
  if (lm == 0) {
    int row0 = rowBase + wave * 16 + lq * 4;
#pragma unroll
    for (int r = 0; r < 4; ++r) atomicAdd(&score[row0 + r], rsum[r]);
  }
}

__global__ __launch_bounds__(256) void k_soft(
    const float* __restrict__ score_src, const float* __restrict__ mask,
    const float* __restrict__ X, const int* __restrict__ gathers,
    float* __restrict__ finalr, int isCtx) {
  const int b = blockIdx.x, tid = threadIdx.x;
  const int n = gathers[b];
  __shared__ float attn[128];
  __shared__ float smax, ssum;
  if (tid < 128) {
    int srow = isCtx ? b : n;
    attn[tid] = score_src[srow * 128 + tid] + (1.0f - mask[b * 128 + tid]) * (-10000.0f);
  }
  __syncthreads();
  if (tid == 0) {
    float m = attn[0];
    for (int i = 1; i < 128; ++i) m = fmaxf(m, attn[i]);
    smax = m;
  }
  __syncthreads();
  if (tid < 128) attn[tid] = expf(attn[tid] - smax);
  __syncthreads();
  if (tid == 0) {
    float s = 0.f;
    for (int i = 0; i < 128; ++i) s += attn[i];
    ssum = 1.0f / s;
  }
  __syncthreads();
  if (tid < 128) attn[tid] *= ssum;
  __syncthreads();
  const float* xb = &X[(size_t)(n << 7) * 1024];
  const int off = isCtx ? 1024 : 0;
  for (int d = tid; d < 1024; d += 256) {
    float a = 0.f;
#pragma unroll 8
    for (int s = 0; s < 128; ++s) a += attn[s] * xb[s * 1024 + d];
    finalr[b * 2048 + off + d] = a;
  }
}

__global__ __launch_bounds__(256) void k_cb_gemm(
    const float* __restrict__ finalr, const float* __restrict__ Wcm,
    float* __restrict__ cb) {
  __shared__ __align__(16) unsigned short As[64 * 32];
  __shared__ __align__(16) unsigned short Bs[64 * 32];
  const int bid = blockIdx.x;
  const int rowBase = (bid >> 4) * 64, colBase = (bid & 15) * 64;
  const int tid = threadIdx.x, wave = tid >> 6, lane = tid & 63;
  const int lm = lane & 15, lq = lane >> 4;
  const int sr = tid >> 2, sc = (tid & 3) * 8;
  f32x4 acc[4] = {};
  for (int k0 = 0; k0 < 1024; k0 += 32) {
    __syncthreads();
    stage8(&As[sr * 32 + sc], &finalr[(size_t)(rowBase + sr) * 2048 + k0 + sc]);
    stage8(&Bs[sr * 32 + sc], &Wcm[(size_t)(colBase + sr) * 1024 + k0 + sc]);
    __syncthreads();
    bf16x8 af = *(const bf16x8*)&As[(wave * 16 + lm) * 32 + lq * 8];
#pragma unroll
    for (int j = 0; j < 4; ++j) {
      bf16x8 bfr = *(const bf16x8*)&Bs[(j * 16 + lm) * 32 + lq * 8];
      acc[j] = __builtin_amdgcn_mfma_f32_16x16x32_bf16(af, bfr, acc[j], 0, 0, 0);
    }
  }
#pragma unroll
  for (int j = 0; j < 4; ++j) {
    int col = colBase + j * 16 + lm;
#pragma unroll
    for (int r = 0; r < 4; ++r) {
      int row = rowBase + wave * 16 + lq * 4 + r;
      cb[row * 1024 + col] = acc[j][r];
    }
  }
}

__global__ __launch_bounds__(256) void k_lat_gemm(
    const float* __restrict__ finalr, const float* __restrict__ Wf2l,
    float* __restrict__ lat) {
  __shared__ __align__(16) unsigned short As[64 * 32];
  __shared__ __align__(16) unsigned short Bs[64 * 32];
  const int rowBase = blockIdx.y * 64, colBase = blockIdx.x * 64;
  const int tid = threadIdx.x, wave = tid >> 6, lane = tid & 63;
  const int lm = lane & 15, lq = lane >> 4;
  const int sr = tid >> 2, sc = (tid & 3) * 8;
  f32x4 acc[4] = {};
  for (int k0 = 0; k0 < 2048; k0 += 32) {
    __syncthreads();
    stage8(&As[sr * 32 + sc], &finalr[(size_t)(rowBase + sr) * 2048 + k0 + sc]);
    int l = colBase + sr;
    if (l < LATENT) {
      stage8(&Bs[sr * 32 + sc], &Wf2l[(size_t)l * 2048 + k0 + sc]);
    } else {
      uint4 z = {0, 0, 0, 0};
      *(uint4*)&Bs[sr * 32 + sc] = z;
    }
    __syncthreads();
    bf16x8 af = *(const bf16x8*)&As[(wave * 16 + lm) * 32 + lq * 8];
#pragma unroll
    for (int j = 0; j < 4; ++j) {
      bf16x8 bfr = *(const bf16x8*)&Bs[(j * 16 + lm) * 32 + lq * 8];
      acc[j] = __builtin_amdgcn_mfma_f32_16x16x32_bf16(af, bfr, acc[j], 0, 0, 0);
    }
  }
#pragma unroll
  for (int j = 0; j < 4; ++j) {
    int col = colBase + j * 16 + lm;
    if (col < LATENT) {
#pragma unroll
      for (int r = 0; r < 4; ++r) {
        int row = rowBase + wave * 16 + lq * 4 + r;
        lat[row * LATENT + col] = acc[j][r];
      }
    }
  }
}

__global__ __launch_bounds__(256) void k_out_gemm(
    const float* __restrict__ finalr, const float* __restrict__ Wout,
    const float* __restrict__ lat, const float* __restrict__ Wl2l,
    const float* __restrict__ lscale, float* __restrict__ out,
    float* __restrict__ outLat) {
  __shared__ __align__(16) unsigned short As[64 * 32];
  __shared__ __align__(16) unsigned short Bs[64 * 32];
  const int rowBase = blockIdx.y * 64, colBase = blockIdx.x * 64;
  const int tid = threadIdx.x, wave = tid >> 6, lane = tid & 63;
  const int lm = lane & 15, lq = lane >> 4;
  const int sr = tid >> 2, sc = (tid & 3) * 8;
  const float scal = lscale[0];
  const int lrow = colBase + sr;
  const bool lvalid = (lrow < LL);
  f32x4 acc[4] = {};
  for (int k0 = 0; k0 < 2048; k0 += 32) {
    __syncthreads();
    stage8(&As[sr * 32 + sc], &finalr[(size_t)(rowBase + sr) * 2048 + k0 + sc]);
    if (lvalid) {
      stage8(&Bs[sr * 32 + sc], &Wout[(size_t)lrow * 2048 + k0 + sc]);
    } else {
      uint4 z = {0, 0, 0, 0};
      *(uint4*)&Bs[sr * 32 + sc] = z;
    }
    __syncthreads();
    bf16x8 af = *(const bf16x8*)&As[(wave * 16 + lm) * 32 + lq * 8];
#pragma unroll
    for (int j = 0; j < 4; ++j) {
      bf16x8 bfr = *(const bf16x8*)&Bs[(j * 16 + lm) * 32 + lq * 8];
      acc[j] = __builtin_amdgcn_mfma_f32_16x16x32_bf16(af, bfr, acc[j], 0, 0, 0);
    }
  }
  f32x4 acc2[4] = {};
  for (int k2 = 0; k2 < 128; k2 += 32) {
    __syncthreads();
    const int brow = rowBase + sr;
#pragma unroll
    for (int jj = 0; jj < 8; ++jj) {
      int idx = k2 + sc + jj;
      As[sr * 32 + sc + jj] = (idx < LATENT) ? f2bf(lat[brow * LATENT + idx]) : (unsigned short)0;
      Bs[sr * 32 + sc + jj] = (lvalid && idx < LATENT) ? f2bf(Wl2l[lrow * LATENT + idx]) : (unsigned short)0;
    }
    __syncthreads();
    bf16x8 af = *(const bf16x8*)&As[(wave * 16 + lm) * 32 + lq * 8];
#pragma unroll
    for (int j = 0; j < 4; ++j) {
      bf16x8 bfr = *(const bf16x8*)&Bs[(j * 16 + lm) * 32 + lq * 8];
      acc2[j] = __builtin_amdgcn_mfma_f32_16x16x32_bf16(af, bfr, acc2[j], 0, 0, 0);
    }
  }
#pragma unroll
  for (int j = 0; j < 4; ++j) {
    int col = colBase + j * 16 + lm;
    if (col < LL) {
#pragma unroll
      for (int r = 0; r < 4; ++r) {
        int row = rowBase + wave * 16 + lq * 4 + r;
        float lv = acc2[j][r];
        out[(size_t)row * LL + col] = acc[j][r] + scal * lv;
        outLat[(size_t)row * LL + col] = lv;
      }
    }
  }
}

extern "C" void kernel_launch(void* const* d_in, const int* in_sizes, int n_in,
                              void* d_out, int out_size, void* d_ws, size_t ws_size,
                              hipStream_t stream) {
  const float* X = (const float*)d_in[0];
  const float* men_mask = (const float*)d_in[1];
  const float* ctx_mask = (const float*)d_in[2];
  const float* dist = (const float*)d_in[3];
  const int* gathers = (const int*)d_in[4];
  const float* W_men_m = (const float*)d_in[5];
  const float* W_men_o = (const float*)d_in[6];
  const float* W_ctx_c = (const float*)d_in[7];
  const float* W_ctx_m = (const float*)d_in[8];
  const float* w_ctx_d = (const float*)d_in[9];
  const float* W_ctx_o = (const float*)d_in[10];
  const float* W_out = (const float*)d_in[11];
  const float* W_f2l = (const float*)d_in[12];
  const float* W_l2l = (const float*)d_in[13];
  const float* lscale = (const float*)d_in[14];
  float* out = (float*)d_out;
  float* outLat = out + (size_t)BB * LL;

  size_t off = 0;
  auto carve = [&](size_t bytes) {
    void* p = (char*)d_ws + off;
    off = (off + bytes + 255) & ~(size_t)255;
    return p;
  };
  float* sent_score = (float*)carve(32768 * 4);
  float* ctx_score = (float*)carve(65536 * 4);
  float* finalr = (float*)carve((size_t)512 * 2048 * 4);        // legacy only
  float* cb = (float*)carve((size_t)512 * 1024 * 4);
  float* lat = (float*)carve((size_t)512 * LATENT * 4);         // legacy only
  unsigned short* Xb = (unsigned short*)carve((size_t)32768 * 1024 * 2);
  unsigned short* Wmb = (unsigned short*)carve((size_t)1024 * 1024 * 2);
  unsigned short* Wcb = (unsigned short*)carve((size_t)1024 * 1024 * 2);
  unsigned short* Wcmb = (unsigned short*)carve((size_t)1024 * 1024 * 2);
  unsigned short* Hc = (unsigned short*)carve((size_t)32768 * 1024 * 2);
  unsigned short* Wf2lb = (unsigned short*)carve((size_t)LATPAD * 2048 * 2);
  unsigned short* Wl2lb = (unsigned short*)carve((size_t)LPAD * LATPAD * 2);
  unsigned short* finalrb = (unsigned short*)carve((size_t)512 * 2048 * 2);
  unsigned short* latb = (unsigned short*)carve((size_t)512 * LATPAD * 2);
  const bool fits = off <= ws_size;
  // Woutb aliases Xb (Xb dead after ctx softmax; LPAD*2048*2 = 42.5 MB <= 67 MB)
  unsigned short* Woutb = Xb;

  if (fits) {
    hipMemsetAsync(sent_score, 0, 32768 * sizeof(float), stream);
    k_cvt<<<8192, 256, 0, stream>>>(X, Xb, 32768 * 1024 / 4);
    k_cvt<<<1024, 256, 0, stream>>>(W_men_m, Wmb, 1024 * 1024 / 4);
    k_cvt<<<1024, 256, 0, stream>>>(W_ctx_c, Wcb, 1024 * 1024 / 4);
    k_cvt<<<1024, 256, 0, stream>>>(W_ctx_m, Wcmb, 1024 * 1024 / 4);
    k_cvt_pad<<<512, 256, 0, stream>>>(W_f2l, Wf2lb, LATENT, 2048, 2048, LATPAD * 2048);
    k_cvt_pad<<<1024, 256, 0, stream>>>(W_l2l, Wl2lb, LL, LATENT, LATPAD, LPAD * LATPAD);
    k_mc_gemm<<<dim3(16, 256), 256, 0, stream>>>(Xb, Wmb, Wcb, W_men_o, sent_score, Hc);
    k_softb<<<512, 256, 0, stream>>>(sent_score, men_mask, Xb, gathers, finalrb, 0);
    k_cb_gemm_b<<<128, 256, 0, stream>>>(finalrb, Wcmb, cb);
    k_ctx_score<<<512, 256, 0, stream>>>(Hc, gathers, cb, w_ctx_d, W_ctx_o, dist, ctx_score);
    k_softb<<<512, 256, 0, stream>>>(ctx_score, ctx_mask, Xb, gathers, finalrb, 1);
    k_lat_gemm_b<<<dim3(2, 8), 256, 0, stream>>>(finalrb, Wf2lb, latb);
    // Xb dead; convert W_out (zero-padded rows) into its space
    k_cvt_pad<<<8192, 256, 0, stream>>>(W_out, Woutb, LL, 2048, 2048, LPAD * 2048);
    k_out_gemm_b<<<dim3(81, 4), 256, 0, stream>>>(finalrb, Woutb, latb, Wl2lb,
                                                  lscale, out, outLat);
  } else {
    hipMemsetAsync(d_ws, 0, (32768 + 65536) * sizeof(float), stream);
    k_men_gemm<<<8192, 256, 0, stream>>>(X, W_men_m, W_men_o, sent_score);
    k_soft<<<512, 256, 0, stream>>>(sent_score, men_mask, X, gathers, finalr, 0);
    k_cb_gemm<<<128, 256, 0, stream>>>(finalr, W_ctx_m, cb);
    k_ctx_gemm<<<16384, 256, 0, stream>>>(X, gathers, W_ctx_c, w_ctx_d, W_ctx_o, dist, cb, ctx_score);
    k_soft<<<512, 256, 0, stream>>>(ctx_score, ctx_mask, X, gathers, finalr, 1);
    k_lat_gemm<<<dim3(2, 8), 256, 0, stream>>>(finalr, W_f2l, lat);
    k_out_gemm<<<dim3(162, 8), 256, 0, stream>>>(finalr, W_out, lat, W_l2l, lscale, out, outLat);
  }
}